// Round 1
// baseline (2062.029 us; speedup 1.0000x reference)
//
#include <hip/hip_runtime.h>
#include <math.h>

#define NFRM 8192   // B*T
#define NPT  128    // N points
#define CH   128    // HID
#define DD   256    // D
#define HH   512    // H
#define SS   16     // S
#define NL   4

// ---------------- helpers ----------------

__device__ __forceinline__ float red256(float v, int tid, volatile float* sc) {
#pragma unroll
  for (int off = 32; off; off >>= 1) v += __shfl_down(v, off);
  __syncthreads();                 // protect scratch from previous call
  if ((tid & 63) == 0) sc[tid >> 6] = v;
  __syncthreads();
  return sc[0] + sc[1] + sc[2] + sc[3];
}

// per-frame point normalization: xn[p][k] = (x - mean_p)/ (std_ddof1 + 1e-10)
__device__ void normalize_points(float xn[NPT][4], int tid, volatile float* sc) {
#pragma unroll
  for (int k = 0; k < 3; ++k) {
    float v = (tid < NPT) ? xn[tid][k] : 0.f;
    float tot = red256(v, tid, sc);
    float mu = tot * (1.f / 128.f);
    float d = (tid < NPT) ? (v - mu) : 0.f;
    float ss = red256(d * d, tid, sc);
    float sd = sqrtf(ss * (1.f / 127.f)) + 1e-10f;
    if (tid < NPT) xn[tid][k] = (v - mu) / sd;
    __syncthreads();
  }
}

__device__ __forceinline__ float sigmoidf_(float x) { return 1.f / (1.f + expf(-x)); }
__device__ __forceinline__ float geluf_(float x) { return 0.5f * x * (1.f + erff(x * 0.70710678118654752f)); }

// ---------------- kernels ----------------

// pack/transpose weights: W2P[k0][c][j]=conv2_w[c][4k0+j]; fprojT[c][d]; inwT[l][k][j]; outwT[l][k][d]
__global__ __launch_bounds__(256) void k_prep(const float* __restrict__ conv2_w,
    const float* __restrict__ fproj_w, const float* __restrict__ in_w, const float* __restrict__ out_w,
    float* __restrict__ W2P, float* __restrict__ fprojT, float* __restrict__ inwT, float* __restrict__ outwT) {
  int idx = blockIdx.x * 256 + threadIdx.x;
  if (idx < 16384) {
    int k0 = idx >> 9, rem = idx & 511, c = rem >> 2, j = rem & 3;
    W2P[idx] = conv2_w[c * 128 + k0 * 4 + j];
    return;
  }
  idx -= 16384;
  if (idx < 32768) { int c = idx >> 8, d = idx & 255; fprojT[idx] = fproj_w[d * 128 + c]; return; }
  idx -= 32768;
  if (idx < 1048576) {
    int l = idx >> 18, rem = idx & 262143, k = rem >> 10, j = rem & 1023;
    inwT[idx] = in_w[(size_t)(l * 1024 + j) * 256 + k];
    return;
  }
  idx -= 1048576;
  if (idx < 524288) {
    int l = idx >> 17, rem = idx & 131071, k = rem >> 8, d = rem & 255;
    outwT[idx] = out_w[(size_t)(l * 256 + d) * 512 + k];
  }
}

// bn1 partial stats: per frame, per channel sum/sumsq of z1 = xn @ conv1_w.T
__global__ __launch_bounds__(256) void k1_bn1(const float* __restrict__ x, const float* __restrict__ conv1_w,
    float* __restrict__ psum, float* __restrict__ psq) {
  __shared__ float xn[NPT][4];
  __shared__ float w1s[384];
  __shared__ float sc[4];
  __shared__ float cmb[2][CH];
  int f = blockIdx.x, tid = threadIdx.x;
  const float* xf = x + (size_t)f * 384;
  for (int i = tid; i < 384; i += 256) { w1s[i] = conv1_w[i]; xn[i / 3][i % 3] = xf[i]; }
  __syncthreads();
  normalize_points(xn, tid, sc);
  __syncthreads();
  int c = tid & 127, ph = tid >> 7;
  float w0 = w1s[c * 3], w1 = w1s[c * 3 + 1], w2 = w1s[c * 3 + 2];
  float sm = 0.f, sq = 0.f;
  for (int i = 0; i < 64; ++i) {
    int p = ph * 64 + i;
    float z = fmaf(xn[p][0], w0, fmaf(xn[p][1], w1, xn[p][2] * w2));
    sm += z; sq += z * z;
  }
  if (ph == 0) { cmb[0][c] = sm; cmb[1][c] = sq; }
  __syncthreads();
  if (ph == 1) {
    psum[(size_t)f * CH + c] = sm + cmb[0][c];
    psq[(size_t)f * CH + c]  = sq + cmb[1][c];
  }
}

// reduce partials -> BN scale/shift: st[c]=s, st[128+c]=t  (y = s*z + t)
__global__ __launch_bounds__(256) void k_red(const float* __restrict__ psum, const float* __restrict__ psq,
    const float* __restrict__ w, const float* __restrict__ b, float* __restrict__ st,
    float invM, float eps) {
  __shared__ float sc[4];
  int c = blockIdx.x, tid = threadIdx.x;
  float sm = 0.f, sq = 0.f;
  for (int f = tid; f < NFRM; f += 256) { sm += psum[(size_t)f * CH + c]; sq += psq[(size_t)f * CH + c]; }
  sm = red256(sm, tid, sc);
  sq = red256(sq, tid, sc);
  if (tid == 0) {
    float mean = sm * invM;
    float var = sq * invM - mean * mean;
    float s = w[c] / sqrtf(var + eps);
    st[c] = s;
    st[CH + c] = b[c] - mean * s;
  }
}

// main fused kernel: xn -> z1 -> h1(bn1,relu) -> z2 = h1 @ W2^T ; emit per-frame max/min + bn2 partials
__global__ __launch_bounds__(256) void k2_main(const float* __restrict__ x, const float* __restrict__ conv1_w,
    const float* __restrict__ s1t1, const float* __restrict__ W2P,
    float* __restrict__ z2mx, float* __restrict__ z2mn,
    float* __restrict__ psum, float* __restrict__ psq) {
  __shared__ float h1[NPT][132];
  __shared__ float xn[NPT][4];
  __shared__ float w1s[384];
  __shared__ float s1s[CH], t1s[CH];
  __shared__ float sc[4];
  __shared__ float cmb[4][CH];
  int f = blockIdx.x, tid = threadIdx.x;
  const float* xf = x + (size_t)f * 384;
  for (int i = tid; i < 384; i += 256) { w1s[i] = conv1_w[i]; xn[i / 3][i % 3] = xf[i]; }
  if (tid < CH) { s1s[tid] = s1t1[tid]; t1s[tid] = s1t1[CH + tid]; }
  __syncthreads();
  normalize_points(xn, tid, sc);
  __syncthreads();
  { // h1 = relu(bn1(xn @ W1^T))
    int p = tid >> 1, chb = (tid & 1) * 64;
    float a0 = xn[p][0], a1 = xn[p][1], a2 = xn[p][2];
    for (int j = 0; j < 64; ++j) {
      int c = chb + j;
      float z = fmaf(a0, w1s[c * 3], fmaf(a1, w1s[c * 3 + 1], a2 * w1s[c * 3 + 2]));
      h1[p][c] = fmaxf(0.f, fmaf(s1s[c], z, t1s[c]));
    }
  }
  __syncthreads();
  int c = tid & 127, ph = tid >> 7;
  float acc[64];
#pragma unroll
  for (int i = 0; i < 64; ++i) acc[i] = 0.f;
  const float4* w2p4 = (const float4*)W2P;
  for (int k0 = 0; k0 < 32; ++k0) {
    float4 w = w2p4[k0 * 128 + c];
#pragma unroll
    for (int i = 0; i < 64; ++i) {
      float4 h = *(const float4*)(&h1[ph * 64 + i][k0 * 4]);
      acc[i] = fmaf(h.x, w.x, fmaf(h.y, w.y, fmaf(h.z, w.z, fmaf(h.w, w.w, acc[i]))));
    }
  }
  float mx = -1e30f, mn = 1e30f, sm = 0.f, sq = 0.f;
#pragma unroll
  for (int i = 0; i < 64; ++i) {
    float v = acc[i];
    mx = fmaxf(mx, v); mn = fminf(mn, v); sm += v; sq += v * v;
  }
  if (ph == 0) { cmb[0][c] = mx; cmb[1][c] = mn; cmb[2][c] = sm; cmb[3][c] = sq; }
  __syncthreads();
  if (ph == 1) {
    z2mx[(size_t)f * CH + c] = fmaxf(mx, cmb[0][c]);
    z2mn[(size_t)f * CH + c] = fminf(mn, cmb[1][c]);
    psum[(size_t)f * CH + c] = sm + cmb[2][c];
    psq[(size_t)f * CH + c]  = sq + cmb[3][c];
  }
}

// feat = relu(bn2(z2ext)) @ fprojT + b ; pre-LN -> seq   (8 frames / block)
__global__ __launch_bounds__(256) void k4_feat(const float* __restrict__ z2mx, const float* __restrict__ z2mn,
    const float* __restrict__ s2t2, const float* __restrict__ fprojT, const float* __restrict__ fpb,
    const float* __restrict__ plw, const float* __restrict__ plb, float* __restrict__ seq) {
  __shared__ float h2[8][CH];
  __shared__ float sc[4];
  int f0 = blockIdx.x * 8, tid = threadIdx.x;
  for (int i = tid; i < 8 * CH; i += 256) {
    int r = i >> 7, c = i & 127;
    float s = s2t2[c], t = s2t2[CH + c];
    float z = (s >= 0.f) ? z2mx[(size_t)(f0 + r) * CH + c] : z2mn[(size_t)(f0 + r) * CH + c];
    h2[r][c] = fmaxf(0.f, fmaf(s, z, t));
  }
  __syncthreads();
  int d = tid;
  float acc[8];
  float bias = fpb[d];
#pragma unroll
  for (int r = 0; r < 8; ++r) acc[r] = bias;
  for (int c = 0; c < CH; ++c) {
    float w = fprojT[c * DD + d];
#pragma unroll
    for (int r = 0; r < 8; ++r) acc[r] = fmaf(h2[r][c], w, acc[r]);
  }
#pragma unroll
  for (int r = 0; r < 8; ++r) {
    float mu = red256(acc[r], tid, sc) * (1.f / 256.f);
    float dd = acc[r] - mu;
    float var = red256(dd * dd, tid, sc) * (1.f / 256.f);
    float rs = 1.f / sqrtf(var + 1e-5f);
    seq[(size_t)(f0 + r) * DD + d] = fmaf(dd * rs, plw[d], plb[d]);
  }
}

// inp = seq @ inwT + b ; gate=sigmoid(:512) upd=silu(512:)   (16 frames / block)
__global__ __launch_bounds__(256) void k_in(const float* __restrict__ seq, const float* __restrict__ inwT,
    const float* __restrict__ inb, float* __restrict__ gate, float* __restrict__ upd) {
  __shared__ float As[16][DD];
  int f0 = blockIdx.x * 16, tid = threadIdx.x;
  const float4* src = (const float4*)(seq + (size_t)f0 * DD);
  for (int i = tid; i < 16 * DD / 4; i += 256) ((float4*)As)[i] = src[i];
  __syncthreads();
  int c0 = tid * 4;
  float acc[16][4];
  float4 bv = *(const float4*)(inb + c0);
#pragma unroll
  for (int r = 0; r < 16; ++r) { acc[r][0] = bv.x; acc[r][1] = bv.y; acc[r][2] = bv.z; acc[r][3] = bv.w; }
  for (int k0 = 0; k0 < 64; ++k0) {
    float4 w0 = *(const float4*)(inwT + (size_t)(k0 * 4 + 0) * 1024 + c0);
    float4 w1 = *(const float4*)(inwT + (size_t)(k0 * 4 + 1) * 1024 + c0);
    float4 w2 = *(const float4*)(inwT + (size_t)(k0 * 4 + 2) * 1024 + c0);
    float4 w3 = *(const float4*)(inwT + (size_t)(k0 * 4 + 3) * 1024 + c0);
#pragma unroll
    for (int r = 0; r < 16; ++r) {
      float4 a = *(const float4*)(&As[r][k0 * 4]);
      acc[r][0] = fmaf(a.x, w0.x, fmaf(a.y, w1.x, fmaf(a.z, w2.x, fmaf(a.w, w3.x, acc[r][0]))));
      acc[r][1] = fmaf(a.x, w0.y, fmaf(a.y, w1.y, fmaf(a.z, w2.y, fmaf(a.w, w3.y, acc[r][1]))));
      acc[r][2] = fmaf(a.x, w0.z, fmaf(a.y, w1.z, fmaf(a.z, w2.z, fmaf(a.w, w3.z, acc[r][2]))));
      acc[r][3] = fmaf(a.x, w0.w, fmaf(a.y, w1.w, fmaf(a.z, w2.w, fmaf(a.w, w3.w, acc[r][3]))));
    }
  }
  bool isGate = (c0 < HH);
  int cb = isGate ? c0 : (c0 - HH);
  float* dst = isGate ? gate : upd;
#pragma unroll
  for (int r = 0; r < 16; ++r) {
    float4 o;
    if (isGate) {
      o.x = sigmoidf_(acc[r][0]); o.y = sigmoidf_(acc[r][1]);
      o.z = sigmoidf_(acc[r][2]); o.w = sigmoidf_(acc[r][3]);
    } else {
      o.x = acc[r][0] * sigmoidf_(acc[r][0]); o.y = acc[r][1] * sigmoidf_(acc[r][1]);
      o.z = acc[r][2] * sigmoidf_(acc[r][2]); o.w = acc[r][3] * sigmoidf_(acc[r][3]);
    }
    *(float4*)(dst + (size_t)(f0 + r) * HH + cb) = o;
  }
}

// depthwise conv along T, kernel 4, pad(2,2) crop :T ; u[t] = w0*x[t-2]+w1*x[t-1]+w2*x[t]+w3*x[t+1] + cb
__global__ __launch_bounds__(256) void k_conv(const float* __restrict__ upd, const float* __restrict__ cw,
    const float* __restrict__ cb, float* __restrict__ u) {
  int idx = blockIdx.x * 256 + threadIdx.x;    // NFRM*HH
  int h = idx & 511, f = idx >> 9;
  int t = f & 511, b = f >> 9;
  const float* col = upd + ((size_t)b * 512) * HH + h;
  float v = cb[h];
  float w0 = cw[h * 4], w1 = cw[h * 4 + 1], w2 = cw[h * 4 + 2], w3 = cw[h * 4 + 3];
  if (t >= 2) v = fmaf(w0, col[(size_t)(t - 2) * HH], v);
  if (t >= 1) v = fmaf(w1, col[(size_t)(t - 1) * HH], v);
  v = fmaf(w2, col[(size_t)t * HH], v);
  if (t + 1 < 512) v = fmaf(w3, col[(size_t)(t + 1) * HH], v);
  u[idx] = v;
}

// Bu[f][s] = sum_h u[f][h]*Bm[h][s], masked   (16 frames x 16 s per block)
__global__ __launch_bounds__(256) void k_bu(const float* __restrict__ u, const float* __restrict__ Bm_l,
    const int* __restrict__ lengths, float* __restrict__ bu) {
  __shared__ float ul[16][HH];
  __shared__ float bml[HH * SS];
  int f0 = blockIdx.x * 16, tid = threadIdx.x;
  const float4* src = (const float4*)(u + (size_t)f0 * HH);
  for (int i = tid; i < 16 * HH / 4; i += 256) ((float4*)ul)[i] = src[i];
  for (int i = tid; i < HH * SS / 4; i += 256) ((float4*)bml)[i] = ((const float4*)Bm_l)[i];
  __syncthreads();
  int s = tid & 15, r = tid >> 4;
  int f = f0 + r, t = f & 511, b = f >> 9;
  float acc = 0.f;
  for (int h = 0; h < HH; ++h) acc = fmaf(ul[r][h], bml[h * SS + s], acc);
  bu[(size_t)f * SS + s] = (t < lengths[b]) ? acc : 0.f;
}

// cumsum over t per (b,s): chunked scan in LDS, one block per b
__global__ __launch_bounds__(256) void k_scan(const float* __restrict__ bu, float* __restrict__ hst) {
  __shared__ float buf[512 * SS];
  __shared__ float tot[16][SS];
  int b = blockIdx.x, tid = threadIdx.x;
  for (int i = tid; i < 512 * SS; i += 256) buf[i] = bu[(size_t)b * 512 * SS + i];
  __syncthreads();
  int s = tid & 15, ck = tid >> 4;
  int base = ck * 32;
  float acc = 0.f;
  for (int i = 0; i < 32; ++i) { acc += buf[(base + i) * SS + s]; buf[(base + i) * SS + s] = acc; }
  tot[ck][s] = acc;
  __syncthreads();
  float off = 0.f;
  for (int c2 = 0; c2 < 16; ++c2) if (c2 < ck) off += tot[c2][s];
  for (int i = 0; i < 32; ++i) buf[(base + i) * SS + s] += off;
  __syncthreads();
  for (int i = tid; i < 512 * SS; i += 256) hst[(size_t)b * 512 * SS + i] = buf[i];
}

// V[h] = (hst . A[h]) * gate * mask ; seq_out = V @ outwT + b   (16 frames / block)
__global__ __launch_bounds__(256) void k_out(const float* __restrict__ hst, const float* __restrict__ gate,
    const float* __restrict__ A_l, const float* __restrict__ outwT, const float* __restrict__ outb,
    const int* __restrict__ lengths, float* __restrict__ sout) {
  __shared__ float V[16][HH];
  __shared__ float al[HH * SS];
  __shared__ float hs[16][SS];
  int f0 = blockIdx.x * 16, tid = threadIdx.x;
  for (int i = tid; i < HH * SS / 4; i += 256) ((float4*)al)[i] = ((const float4*)A_l)[i];
  hs[tid >> 4][tid & 15] = hst[(size_t)f0 * SS + tid];
  __syncthreads();
  for (int i = tid; i < 16 * HH; i += 256) {
    int r = i >> 9, h = i & 511;
    int f = f0 + r, t = f & 511, b = f >> 9;
    float a = 0.f;
#pragma unroll
    for (int s2 = 0; s2 < SS; ++s2) a = fmaf(hs[r][s2], al[h * SS + s2], a);
    float g = gate[(size_t)f * HH + h];
    V[r][h] = (t < lengths[b]) ? a * g : 0.f;
  }
  __syncthreads();
  int d = tid;
  float acc[16];
  float bias = outb[d];
#pragma unroll
  for (int r = 0; r < 16; ++r) acc[r] = bias;
  for (int k0 = 0; k0 < 128; ++k0) {
    float w0 = outwT[(size_t)(k0 * 4 + 0) * DD + d];
    float w1 = outwT[(size_t)(k0 * 4 + 1) * DD + d];
    float w2 = outwT[(size_t)(k0 * 4 + 2) * DD + d];
    float w3 = outwT[(size_t)(k0 * 4 + 3) * DD + d];
#pragma unroll
    for (int r = 0; r < 16; ++r) {
      float4 v = *(const float4*)(&V[r][k0 * 4]);
      acc[r] = fmaf(v.x, w0, fmaf(v.y, w1, fmaf(v.z, w2, fmaf(v.w, w3, acc[r]))));
    }
  }
#pragma unroll
  for (int r = 0; r < 16; ++r) sout[(size_t)(f0 + r) * DD + d] = acc[r];
}

// post-LN per frame
__global__ __launch_bounds__(256) void k_postln(const float* __restrict__ seq, const float* __restrict__ w,
    const float* __restrict__ b, float* __restrict__ out) {
  __shared__ float sc[4];
  int f = blockIdx.x, tid = threadIdx.x;
  float v = seq[(size_t)f * DD + tid];
  float mu = red256(v, tid, sc) * (1.f / 256.f);
  float dd = v - mu;
  float var = red256(dd * dd, tid, sc) * (1.f / 256.f);
  float rs = 1.f / sqrtf(var + 1e-5f);
  out[(size_t)f * DD + tid] = fmaf(dd * rs, w[tid], b[tid]);
}

// masked mean pool over t (one block per b)
__global__ __launch_bounds__(256) void k_pool(const float* __restrict__ lnseq, const int* __restrict__ lengths,
    float* __restrict__ pooled) {
  int b = blockIdx.x, d = threadIdx.x;
  int len = lengths[b];
  float acc = 0.f;
  for (int t = 0; t < len; ++t) acc += lnseq[((size_t)b * 512 + t) * DD + d];
  pooled[b * DD + d] = acc / (float)max(len, 1);
}

// 16-row MLP layer: out[16][Nout] = act(in[16][K] @ W^T + b)
__global__ __launch_bounds__(256) void k_mlp(const float* __restrict__ in, const float* __restrict__ W,
    const float* __restrict__ bias, float* __restrict__ out, int K, int Nout, int act) {
  __shared__ float lin[16 * 1024];
  int tid = threadIdx.x;
  for (int i = tid; i < 16 * K; i += 256) lin[i] = in[i];
  __syncthreads();
  int o = blockIdx.x * 256 + tid;
  float acc[16];
  float bv = bias[o];
#pragma unroll
  for (int r = 0; r < 16; ++r) acc[r] = bv;
  for (int k = 0; k < K; ++k) {
    float w = W[(size_t)o * K + k];
#pragma unroll
    for (int r = 0; r < 16; ++r) acc[r] = fmaf(lin[r * K + k], w, acc[r]);
  }
#pragma unroll
  for (int r = 0; r < 16; ++r) {
    float v = acc[r];
    if (act) v = geluf_(v);
    out[(size_t)r * Nout + o] = v;
  }
}

// L2 normalize rows of e[16][512]
__global__ __launch_bounds__(256) void k_norm(const float* __restrict__ e, float* __restrict__ out) {
  __shared__ float sc[4];
  int b = blockIdx.x, tid = threadIdx.x;
  float v0 = e[(size_t)b * 512 + tid], v1 = e[(size_t)b * 512 + 256 + tid];
  float ss = red256(v0 * v0 + v1 * v1, tid, sc);
  float nrm = fmaxf(sqrtf(ss), 1e-12f);
  out[(size_t)b * 512 + tid] = v0 / nrm;
  out[(size_t)b * 512 + 256 + tid] = v1 / nrm;
}

// ---------------- launch ----------------

extern "C" void kernel_launch(void* const* d_in, const int* in_sizes, int n_in,
                              void* d_out, int out_size, void* d_ws, size_t ws_size,
                              hipStream_t stream) {
  const float* x         = (const float*)d_in[0];
  const int*   lengths   = (const int*)d_in[1];
  const float* conv1_w   = (const float*)d_in[2];
  const float* bn1_w     = (const float*)d_in[3];
  const float* bn1_b     = (const float*)d_in[4];
  const float* conv2_w   = (const float*)d_in[5];
  const float* bn2_w     = (const float*)d_in[6];
  const float* bn2_b     = (const float*)d_in[7];
  const float* fproj_w   = (const float*)d_in[8];
  const float* fproj_b   = (const float*)d_in[9];
  const float* pre_ln_w  = (const float*)d_in[10];
  const float* pre_ln_b  = (const float*)d_in[11];
  const float* in_w      = (const float*)d_in[12];
  const float* in_b      = (const float*)d_in[13];
  const float* conv_w    = (const float*)d_in[14];
  const float* conv_b    = (const float*)d_in[15];
  const float* A         = (const float*)d_in[16];
  const float* Bm        = (const float*)d_in[17];
  const float* out_w     = (const float*)d_in[18];
  const float* out_b     = (const float*)d_in[19];
  const float* post_ln_w = (const float*)d_in[20];
  const float* post_ln_b = (const float*)d_in[21];
  const float* m1_w      = (const float*)d_in[22];
  const float* m1_b      = (const float*)d_in[23];
  const float* m2_w      = (const float*)d_in[24];
  const float* m2_b      = (const float*)d_in[25];
  const float* m3_w      = (const float*)d_in[26];
  const float* m3_b      = (const float*)d_in[27];
  float* outp = (float*)d_out;

  float* wsf = (float*)d_ws;
  size_t o = 0;
  auto F32 = [&](size_t n) { float* p = wsf + o; o += (n + 63) & ~(size_t)63; return p; };
  float* psum   = F32(1048576);
  float* psq    = F32(1048576);
  float* z2mx   = F32(1048576);
  float* z2mn   = F32(1048576);
  float* gatev  = psum;              // alias: psum..z2mn (4M floats) reused after K4
  float* s1t1   = F32(256);
  float* s2t2   = F32(256);
  float* W2P    = F32(16384);
  float* fprojT = F32(32768);
  float* inwT   = F32(1048576);
  float* outwT  = F32(524288);
  float* seqA   = F32(2097152);
  float* seqB   = F32(2097152);
  float* updv   = F32(4194304);
  float* uv     = F32(4194304);
  float* buv    = F32(131072);
  float* hstv   = F32(131072);
  float* pooled = F32(4096);
  float* e1     = F32(16384);
  float* e2     = F32(16384);
  float* e3     = F32(8192);
  if (ws_size < o * sizeof(float)) return;  // insufficient scratch (loud failure)

  const float invM = 1.f / (float)(NFRM * NPT);

  k_prep<<<6336, 256, 0, stream>>>(conv2_w, fproj_w, in_w, out_w, W2P, fprojT, inwT, outwT);
  k1_bn1<<<NFRM, 256, 0, stream>>>(x, conv1_w, psum, psq);
  k_red<<<CH, 256, 0, stream>>>(psum, psq, bn1_w, bn1_b, s1t1, invM, 1e-5f);
  k2_main<<<NFRM, 256, 0, stream>>>(x, conv1_w, s1t1, W2P, z2mx, z2mn, psum, psq);
  k_red<<<CH, 256, 0, stream>>>(psum, psq, bn2_w, bn2_b, s2t2, invM, 1e-5f);
  k4_feat<<<NFRM / 8, 256, 0, stream>>>(z2mx, z2mn, s2t2, fprojT, fproj_b, pre_ln_w, pre_ln_b, seqA);

  for (int l = 0; l < NL; ++l) {
    const float* sin = (l & 1) ? seqB : seqA;
    float* sout      = (l & 1) ? seqA : seqB;
    k_in<<<NFRM / 16, 256, 0, stream>>>(sin, inwT + (size_t)l * 262144, in_b + l * 1024, gatev, updv);
    k_conv<<<NFRM * HH / 256, 256, 0, stream>>>(updv, conv_w + l * 2048, conv_b + l * 512, uv);
    k_bu<<<NFRM / 16, 256, 0, stream>>>(uv, Bm + l * 8192, lengths, buv);
    k_scan<<<16, 256, 0, stream>>>(buv, hstv);
    k_out<<<NFRM / 16, 256, 0, stream>>>(hstv, gatev, A + l * 8192, outwT + (size_t)l * 131072,
                                         out_b + l * 256, lengths, sout);
  }
  // after 4 layers seq is in seqA
  k_postln<<<NFRM, 256, 0, stream>>>(seqA, post_ln_w, post_ln_b, seqB);
  k_pool<<<16, 256, 0, stream>>>(seqB, lengths, pooled);
  k_mlp<<<4, 256, 0, stream>>>(pooled, m1_w, m1_b, e1, 256, 1024, 1);
  k_mlp<<<4, 256, 0, stream>>>(e1, m2_w, m2_b, e2, 1024, 1024, 1);
  k_mlp<<<2, 256, 0, stream>>>(e2, m3_w, m3_b, e3, 1024, 512, 0);
  k_norm<<<16, 256, 0, stream>>>(e3, outp);
}

// Round 2
// 1321.278 us; speedup vs baseline: 1.5606x; 1.5606x over previous
//
#include <hip/hip_runtime.h>
#include <math.h>

#define NFRM 8192   // B*T
#define NPT  128    // N points
#define CH   128    // HID
#define DD   256    // D
#define HH   512    // H
#define SS   16     // S
#define NL   4

typedef __attribute__((ext_vector_type(8))) short bf16x8;
typedef __attribute__((ext_vector_type(4))) float f32x4;

// ---------------- helpers ----------------

__device__ __forceinline__ float red256(float v, int tid, volatile float* sc) {
#pragma unroll
  for (int off = 32; off; off >>= 1) v += __shfl_down(v, off);
  __syncthreads();                 // protect scratch from previous call
  if ((tid & 63) == 0) sc[tid >> 6] = v;
  __syncthreads();
  return sc[0] + sc[1] + sc[2] + sc[3];
}

// per-frame point normalization: xn[p][k] = (x - mean_p)/ (std_ddof1 + 1e-10)
__device__ void normalize_points(float xn[NPT][4], int tid, volatile float* sc) {
#pragma unroll
  for (int k = 0; k < 3; ++k) {
    float v = (tid < NPT) ? xn[tid][k] : 0.f;
    float tot = red256(v, tid, sc);
    float mu = tot * (1.f / 128.f);
    float d = (tid < NPT) ? (v - mu) : 0.f;
    float ss = red256(d * d, tid, sc);
    float sd = sqrtf(ss * (1.f / 127.f)) + 1e-10f;
    if (tid < NPT) xn[tid][k] = (v - mu) / sd;
    __syncthreads();
  }
}

__device__ __forceinline__ float sigmoidf_(float x) { return 1.f / (1.f + expf(-x)); }
__device__ __forceinline__ float geluf_(float x) { return 0.5f * x * (1.f + erff(x * 0.70710678118654752f)); }

// manual round-to-nearest-even f32 -> bf16 bits (values are finite; no NaN path needed)
__device__ __forceinline__ unsigned short f2bf(float f) {
  union { float f; unsigned int u; } v; v.f = f;
  unsigned int r = v.u + 0x7FFFu + ((v.u >> 16) & 1u);
  return (unsigned short)(r >> 16);
}

// ---------------- kernels ----------------

// pack/transpose weights:
//   W2B  : bf16, pre-swizzled [c][ (kchunk ^ (c&7))*8 + (k&7) ]  (16B-chunk XOR swizzle, T2)
//   fprojT[c][d]; inwT[l][k][j]; outwT[l][k][d]
__global__ __launch_bounds__(256) void k_prep(const float* __restrict__ conv2_w,
    const float* __restrict__ fproj_w, const float* __restrict__ in_w, const float* __restrict__ out_w,
    unsigned short* __restrict__ W2B, float* __restrict__ fprojT, float* __restrict__ inwT,
    float* __restrict__ outwT) {
  int idx = blockIdx.x * 256 + threadIdx.x;
  if (idx < 16384) {
    int c = idx >> 7, k = idx & 127;
    int dst = c * 128 + ((((k >> 3) ^ (c & 7)) << 3) | (k & 7));
    W2B[dst] = f2bf(conv2_w[idx]);
    return;
  }
  idx -= 16384;
  if (idx < 32768) { int c = idx >> 8, d = idx & 255; fprojT[idx] = fproj_w[d * 128 + c]; return; }
  idx -= 32768;
  if (idx < 1048576) {
    int l = idx >> 18, rem = idx & 262143, k = rem >> 10, j = rem & 1023;
    inwT[idx] = in_w[(size_t)(l * 1024 + j) * 256 + k];
    return;
  }
  idx -= 1048576;
  if (idx < 524288) {
    int l = idx >> 17, rem = idx & 131071, k = rem >> 8, d = rem & 255;
    outwT[idx] = out_w[(size_t)(l * 256 + d) * 512 + k];
  }
}

// bn1 partial stats: per frame, per channel sum/sumsq of z1 = xn @ conv1_w.T
__global__ __launch_bounds__(256) void k1_bn1(const float* __restrict__ x, const float* __restrict__ conv1_w,
    float* __restrict__ psum, float* __restrict__ psq) {
  __shared__ float xn[NPT][4];
  __shared__ float w1s[384];
  __shared__ float sc[4];
  __shared__ float cmb[2][CH];
  int f = blockIdx.x, tid = threadIdx.x;
  const float* xf = x + (size_t)f * 384;
  for (int i = tid; i < 384; i += 256) { w1s[i] = conv1_w[i]; xn[i / 3][i % 3] = xf[i]; }
  __syncthreads();
  normalize_points(xn, tid, sc);
  __syncthreads();
  int c = tid & 127, ph = tid >> 7;
  float w0 = w1s[c * 3], w1 = w1s[c * 3 + 1], w2 = w1s[c * 3 + 2];
  float sm = 0.f, sq = 0.f;
  for (int i = 0; i < 64; ++i) {
    int p = ph * 64 + i;
    float z = fmaf(xn[p][0], w0, fmaf(xn[p][1], w1, xn[p][2] * w2));
    sm += z; sq += z * z;
  }
  if (ph == 0) { cmb[0][c] = sm; cmb[1][c] = sq; }
  __syncthreads();
  if (ph == 1) {
    psum[(size_t)f * CH + c] = sm + cmb[0][c];
    psq[(size_t)f * CH + c]  = sq + cmb[1][c];
  }
}

// reduce partials -> BN scale/shift: st[c]=s, st[128+c]=t  (y = s*z + t)
__global__ __launch_bounds__(256) void k_red(const float* __restrict__ psum, const float* __restrict__ psq,
    const float* __restrict__ w, const float* __restrict__ b, float* __restrict__ st,
    float invM, float eps) {
  __shared__ float sc[4];
  int c = blockIdx.x, tid = threadIdx.x;
  float sm = 0.f, sq = 0.f;
  for (int f = tid; f < NFRM; f += 256) { sm += psum[(size_t)f * CH + c]; sq += psq[(size_t)f * CH + c]; }
  sm = red256(sm, tid, sc);
  sq = red256(sq, tid, sc);
  if (tid == 0) {
    float mean = sm * invM;
    float var = sq * invM - mean * mean;
    float s = w[c] / sqrtf(var + eps);
    st[c] = s;
    st[CH + c] = b[c] - mean * s;
  }
}

// main fused kernel (MFMA): xn -> h1(bf16, swizzled LDS) ; z2 = h1 @ W2^T via mfma_f32_16x16x32_bf16
// emit per-frame per-channel max/min + bn2 partial sum/sumsq
__global__ __launch_bounds__(256) void k2_main(const float* __restrict__ x, const float* __restrict__ conv1_w,
    const float* __restrict__ s1t1, const unsigned short* __restrict__ W2B,
    float* __restrict__ z2mx, float* __restrict__ z2mn,
    float* __restrict__ psum, float* __restrict__ psq) {
  __shared__ alignas(16) unsigned short h1s[16384];  // [p][k] bf16, 16B-chunk XOR swizzle by (p&7)
  __shared__ alignas(16) unsigned short w2s[16384];  // [c][k] bf16, pre-swizzled in global
  __shared__ float xn[NPT][4];
  __shared__ float w1s[384];
  __shared__ float s1s[CH], t1s[CH];
  __shared__ float sc[4];
  __shared__ float smx[4][CH], smn[4][CH], ssm[4][CH], ssq[4][CH];
  int f = blockIdx.x, tid = threadIdx.x;
  const float* xf = x + (size_t)f * 384;
  for (int i = tid; i < 384; i += 256) { w1s[i] = conv1_w[i]; xn[i / 3][i % 3] = xf[i]; }
  if (tid < CH) { s1s[tid] = s1t1[tid]; t1s[tid] = s1t1[CH + tid]; }
  // stage W2 (already swizzled in global): linear coalesced 32 KB copy
  {
    const float4* g4 = (const float4*)W2B;
    float4* s4 = (float4*)w2s;
    for (int i = tid; i < 2048; i += 256) s4[i] = g4[i];
  }
  __syncthreads();
  normalize_points(xn, tid, sc);
  __syncthreads();
  { // h1 = relu(bn1(xn @ W1^T)) -> bf16, swizzled write (b128, 2-way max conflict)
    int p = tid >> 1, half = tid & 1;
    float a0 = xn[p][0], a1 = xn[p][1], a2 = xn[p][2];
#pragma unroll
    for (int j = 0; j < 8; ++j) {
      int chunk = half * 8 + j;
      int c0 = chunk * 8;
      bf16x8 v;
#pragma unroll
      for (int q = 0; q < 8; ++q) {
        int c = c0 + q;
        float z = fmaf(a0, w1s[c * 3], fmaf(a1, w1s[c * 3 + 1], a2 * w1s[c * 3 + 2]));
        float h = fmaxf(0.f, fmaf(s1s[c], z, t1s[c]));
        v[q] = (short)f2bf(h);
      }
      *(bf16x8*)&h1s[p * 128 + ((chunk ^ (p & 7)) << 3)] = v;
    }
  }
  __syncthreads();
  // GEMM: wave w computes rows [w*32, w*32+32) x cols [0,128)
  int lane = tid & 63, w = tid >> 6;
  int lr = lane & 15;     // row/col within fragment
  int kg = lane >> 4;     // k-group
  f32x4 acc[2][8];
#pragma unroll
  for (int fr = 0; fr < 2; ++fr)
#pragma unroll
    for (int fc = 0; fc < 8; ++fc) acc[fr][fc] = (f32x4){0.f, 0.f, 0.f, 0.f};
#pragma unroll
  for (int ks = 0; ks < 4; ++ks) {
    int kchunk = ks * 4 + kg;
    bf16x8 a[2], b[8];
#pragma unroll
    for (int fr = 0; fr < 2; ++fr) {
      int row = w * 32 + fr * 16 + lr;
      a[fr] = *(const bf16x8*)&h1s[row * 128 + ((kchunk ^ (row & 7)) << 3)];
    }
#pragma unroll
    for (int fc = 0; fc < 8; ++fc) {
      int col = fc * 16 + lr;
      b[fc] = *(const bf16x8*)&w2s[col * 128 + ((kchunk ^ (col & 7)) << 3)];
    }
#pragma unroll
    for (int fr = 0; fr < 2; ++fr)
#pragma unroll
      for (int fc = 0; fc < 8; ++fc)
        acc[fr][fc] = __builtin_amdgcn_mfma_f32_16x16x32_bf16(a[fr], b[fc], acc[fr][fc], 0, 0, 0);
  }
  // per-channel stats: lane holds col = fc*16+lr, rows = w*32 + fr*16 + kg*4 + r
#pragma unroll
  for (int fc = 0; fc < 8; ++fc) {
    float mx = -3e38f, mn = 3e38f, sm = 0.f, sq = 0.f;
#pragma unroll
    for (int fr = 0; fr < 2; ++fr)
#pragma unroll
      for (int r = 0; r < 4; ++r) {
        float v = acc[fr][fc][r];
        mx = fmaxf(mx, v); mn = fminf(mn, v); sm += v; sq = fmaf(v, v, sq);
      }
#pragma unroll
    for (int off = 16; off <= 32; off <<= 1) {
      mx = fmaxf(mx, __shfl_xor(mx, off));
      mn = fminf(mn, __shfl_xor(mn, off));
      sm += __shfl_xor(sm, off);
      sq += __shfl_xor(sq, off);
    }
    if (lane < 16) {
      int col = fc * 16 + lr;
      smx[w][col] = mx; smn[w][col] = mn; ssm[w][col] = sm; ssq[w][col] = sq;
    }
  }
  __syncthreads();
  if (tid < CH) {
    float mx = smx[0][tid], mn = smn[0][tid], sm = ssm[0][tid], sq = ssq[0][tid];
#pragma unroll
    for (int w2 = 1; w2 < 4; ++w2) {
      mx = fmaxf(mx, smx[w2][tid]); mn = fminf(mn, smn[w2][tid]);
      sm += ssm[w2][tid]; sq += ssq[w2][tid];
    }
    z2mx[(size_t)f * CH + tid] = mx;
    z2mn[(size_t)f * CH + tid] = mn;
    psum[(size_t)f * CH + tid] = sm;
    psq[(size_t)f * CH + tid]  = sq;
  }
}

// feat = relu(bn2(z2ext)) @ fprojT + b ; pre-LN -> seq   (8 frames / block)
__global__ __launch_bounds__(256) void k4_feat(const float* __restrict__ z2mx, const float* __restrict__ z2mn,
    const float* __restrict__ s2t2, const float* __restrict__ fprojT, const float* __restrict__ fpb,
    const float* __restrict__ plw, const float* __restrict__ plb, float* __restrict__ seq) {
  __shared__ float h2[8][CH];
  __shared__ float sc[4];
  int f0 = blockIdx.x * 8, tid = threadIdx.x;
  for (int i = tid; i < 8 * CH; i += 256) {
    int r = i >> 7, c = i & 127;
    float s = s2t2[c], t = s2t2[CH + c];
    float z = (s >= 0.f) ? z2mx[(size_t)(f0 + r) * CH + c] : z2mn[(size_t)(f0 + r) * CH + c];
    h2[r][c] = fmaxf(0.f, fmaf(s, z, t));
  }
  __syncthreads();
  int d = tid;
  float acc[8];
  float bias = fpb[d];
#pragma unroll
  for (int r = 0; r < 8; ++r) acc[r] = bias;
  for (int c = 0; c < CH; ++c) {
    float w = fprojT[c * DD + d];
#pragma unroll
    for (int r = 0; r < 8; ++r) acc[r] = fmaf(h2[r][c], w, acc[r]);
  }
#pragma unroll
  for (int r = 0; r < 8; ++r) {
    float mu = red256(acc[r], tid, sc) * (1.f / 256.f);
    float dd = acc[r] - mu;
    float var = red256(dd * dd, tid, sc) * (1.f / 256.f);
    float rs = 1.f / sqrtf(var + 1e-5f);
    seq[(size_t)(f0 + r) * DD + d] = fmaf(dd * rs, plw[d], plb[d]);
  }
}

// inp = seq @ inwT + b ; gate=sigmoid(:512) upd=silu(512:)   (16 frames / block)
__global__ __launch_bounds__(256) void k_in(const float* __restrict__ seq, const float* __restrict__ inwT,
    const float* __restrict__ inb, float* __restrict__ gate, float* __restrict__ upd) {
  __shared__ float As[16][DD];
  int f0 = blockIdx.x * 16, tid = threadIdx.x;
  const float4* src = (const float4*)(seq + (size_t)f0 * DD);
  for (int i = tid; i < 16 * DD / 4; i += 256) ((float4*)As)[i] = src[i];
  __syncthreads();
  int c0 = tid * 4;
  float acc[16][4];
  float4 bv = *(const float4*)(inb + c0);
#pragma unroll
  for (int r = 0; r < 16; ++r) { acc[r][0] = bv.x; acc[r][1] = bv.y; acc[r][2] = bv.z; acc[r][3] = bv.w; }
  for (int k0 = 0; k0 < 64; ++k0) {
    float4 w0 = *(const float4*)(inwT + (size_t)(k0 * 4 + 0) * 1024 + c0);
    float4 w1 = *(const float4*)(inwT + (size_t)(k0 * 4 + 1) * 1024 + c0);
    float4 w2 = *(const float4*)(inwT + (size_t)(k0 * 4 + 2) * 1024 + c0);
    float4 w3 = *(const float4*)(inwT + (size_t)(k0 * 4 + 3) * 1024 + c0);
#pragma unroll
    for (int r = 0; r < 16; ++r) {
      float4 a = *(const float4*)(&As[r][k0 * 4]);
      acc[r][0] = fmaf(a.x, w0.x, fmaf(a.y, w1.x, fmaf(a.z, w2.x, fmaf(a.w, w3.x, acc[r][0]))));
      acc[r][1] = fmaf(a.x, w0.y, fmaf(a.y, w1.y, fmaf(a.z, w2.y, fmaf(a.w, w3.y, acc[r][1]))));
      acc[r][2] = fmaf(a.x, w0.z, fmaf(a.y, w1.z, fmaf(a.z, w2.z, fmaf(a.w, w3.z, acc[r][2]))));
      acc[r][3] = fmaf(a.x, w0.w, fmaf(a.y, w1.w, fmaf(a.z, w2.w, fmaf(a.w, w3.w, acc[r][3]))));
    }
  }
  bool isGate = (c0 < HH);
  int cb = isGate ? c0 : (c0 - HH);
  float* dst = isGate ? gate : upd;
#pragma unroll
  for (int r = 0; r < 16; ++r) {
    float4 o;
    if (isGate) {
      o.x = sigmoidf_(acc[r][0]); o.y = sigmoidf_(acc[r][1]);
      o.z = sigmoidf_(acc[r][2]); o.w = sigmoidf_(acc[r][3]);
    } else {
      o.x = acc[r][0] * sigmoidf_(acc[r][0]); o.y = acc[r][1] * sigmoidf_(acc[r][1]);
      o.z = acc[r][2] * sigmoidf_(acc[r][2]); o.w = acc[r][3] * sigmoidf_(acc[r][3]);
    }
    *(float4*)(dst + (size_t)(f0 + r) * HH + cb) = o;
  }
}

// depthwise conv along T, kernel 4, pad(2,2) crop :T ; u[t] = w0*x[t-2]+w1*x[t-1]+w2*x[t]+w3*x[t+1] + cb
__global__ __launch_bounds__(256) void k_conv(const float* __restrict__ upd, const float* __restrict__ cw,
    const float* __restrict__ cb, float* __restrict__ u) {
  int idx = blockIdx.x * 256 + threadIdx.x;    // NFRM*HH
  int h = idx & 511, f = idx >> 9;
  int t = f & 511, b = f >> 9;
  const float* col = upd + ((size_t)b * 512) * HH + h;
  float v = cb[h];
  float w0 = cw[h * 4], w1 = cw[h * 4 + 1], w2 = cw[h * 4 + 2], w3 = cw[h * 4 + 3];
  if (t >= 2) v = fmaf(w0, col[(size_t)(t - 2) * HH], v);
  if (t >= 1) v = fmaf(w1, col[(size_t)(t - 1) * HH], v);
  v = fmaf(w2, col[(size_t)t * HH], v);
  if (t + 1 < 512) v = fmaf(w3, col[(size_t)(t + 1) * HH], v);
  u[idx] = v;
}

// Bu[f][s] = sum_h u[f][h]*Bm[h][s], masked   (16 frames x 16 s per block)
__global__ __launch_bounds__(256) void k_bu(const float* __restrict__ u, const float* __restrict__ Bm_l,
    const int* __restrict__ lengths, float* __restrict__ bu) {
  __shared__ float ul[16][HH];
  __shared__ float bml[HH * SS];
  int f0 = blockIdx.x * 16, tid = threadIdx.x;
  const float4* src = (const float4*)(u + (size_t)f0 * HH);
  for (int i = tid; i < 16 * HH / 4; i += 256) ((float4*)ul)[i] = src[i];
  for (int i = tid; i < HH * SS / 4; i += 256) ((float4*)bml)[i] = ((const float4*)Bm_l)[i];
  __syncthreads();
  int s = tid & 15, r = tid >> 4;
  int f = f0 + r, t = f & 511, b = f >> 9;
  float acc = 0.f;
  for (int h = 0; h < HH; ++h) acc = fmaf(ul[r][h], bml[h * SS + s], acc);
  bu[(size_t)f * SS + s] = (t < lengths[b]) ? acc : 0.f;
}

// cumsum over t per (b,s): chunked scan in LDS, one block per b
__global__ __launch_bounds__(256) void k_scan(const float* __restrict__ bu, float* __restrict__ hst) {
  __shared__ float buf[512 * SS];
  __shared__ float tot[16][SS];
  int b = blockIdx.x, tid = threadIdx.x;
  for (int i = tid; i < 512 * SS; i += 256) buf[i] = bu[(size_t)b * 512 * SS + i];
  __syncthreads();
  int s = tid & 15, ck = tid >> 4;
  int base = ck * 32;
  float acc = 0.f;
  for (int i = 0; i < 32; ++i) { acc += buf[(base + i) * SS + s]; buf[(base + i) * SS + s] = acc; }
  tot[ck][s] = acc;
  __syncthreads();
  float off = 0.f;
  for (int c2 = 0; c2 < 16; ++c2) if (c2 < ck) off += tot[c2][s];
  for (int i = 0; i < 32; ++i) buf[(base + i) * SS + s] += off;
  __syncthreads();
  for (int i = tid; i < 512 * SS; i += 256) hst[(size_t)b * 512 * SS + i] = buf[i];
}

// V[h] = (hst . A[h]) * gate * mask ; seq_out = V @ outwT + b   (16 frames / block)
__global__ __launch_bounds__(256) void k_out(const float* __restrict__ hst, const float* __restrict__ gate,
    const float* __restrict__ A_l, const float* __restrict__ outwT, const float* __restrict__ outb,
    const int* __restrict__ lengths, float* __restrict__ sout) {
  __shared__ float V[16][HH];
  __shared__ float al[HH * SS];
  __shared__ float hs[16][SS];
  int f0 = blockIdx.x * 16, tid = threadIdx.x;
  for (int i = tid; i < HH * SS / 4; i += 256) ((float4*)al)[i] = ((const float4*)A_l)[i];
  hs[tid >> 4][tid & 15] = hst[(size_t)f0 * SS + tid];
  __syncthreads();
  for (int i = tid; i < 16 * HH; i += 256) {
    int r = i >> 9, h = i & 511;
    int f = f0 + r, t = f & 511, b = f >> 9;
    float a = 0.f;
#pragma unroll
    for (int s2 = 0; s2 < SS; ++s2) a = fmaf(hs[r][s2], al[h * SS + s2], a);
    float g = gate[(size_t)f * HH + h];
    V[r][h] = (t < lengths[b]) ? a * g : 0.f;
  }
  __syncthreads();
  int d = tid;
  float acc[16];
  float bias = outb[d];
#pragma unroll
  for (int r = 0; r < 16; ++r) acc[r] = bias;
  for (int k0 = 0; k0 < 128; ++k0) {
    float w0 = outwT[(size_t)(k0 * 4 + 0) * DD + d];
    float w1 = outwT[(size_t)(k0 * 4 + 1) * DD + d];
    float w2 = outwT[(size_t)(k0 * 4 + 2) * DD + d];
    float w3 = outwT[(size_t)(k0 * 4 + 3) * DD + d];
#pragma unroll
    for (int r = 0; r < 16; ++r) {
      float4 v = *(const float4*)(&V[r][k0 * 4]);
      acc[r] = fmaf(v.x, w0, fmaf(v.y, w1, fmaf(v.z, w2, fmaf(v.w, w3, acc[r]))));
    }
  }
#pragma unroll
  for (int r = 0; r < 16; ++r) sout[(size_t)(f0 + r) * DD + d] = acc[r];
}

// post-LN per frame
__global__ __launch_bounds__(256) void k_postln(const float* __restrict__ seq, const float* __restrict__ w,
    const float* __restrict__ b, float* __restrict__ out) {
  __shared__ float sc[4];
  int f = blockIdx.x, tid = threadIdx.x;
  float v = seq[(size_t)f * DD + tid];
  float mu = red256(v, tid, sc) * (1.f / 256.f);
  float dd = v - mu;
  float var = red256(dd * dd, tid, sc) * (1.f / 256.f);
  float rs = 1.f / sqrtf(var + 1e-5f);
  out[(size_t)f * DD + tid] = fmaf(dd * rs, w[tid], b[tid]);
}

// masked mean pool over t (one block per b)
__global__ __launch_bounds__(256) void k_pool(const float* __restrict__ lnseq, const int* __restrict__ lengths,
    float* __restrict__ pooled) {
  int b = blockIdx.x, d = threadIdx.x;
  int len = lengths[b];
  float acc = 0.f;
  for (int t = 0; t < len; ++t) acc += lnseq[((size_t)b * 512 + t) * DD + d];
  pooled[b * DD + d] = acc / (float)max(len, 1);
}

// 16-row MLP layer: out[16][Nout] = act(in[16][K] @ W^T + b)
__global__ __launch_bounds__(256) void k_mlp(const float* __restrict__ in, const float* __restrict__ W,
    const float* __restrict__ bias, float* __restrict__ out, int K, int Nout, int act) {
  __shared__ float lin[16 * 1024];
  int tid = threadIdx.x;
  for (int i = tid; i < 16 * K; i += 256) lin[i] = in[i];
  __syncthreads();
  int o = blockIdx.x * 256 + tid;
  float acc[16];
  float bv = bias[o];
#pragma unroll
  for (int r = 0; r < 16; ++r) acc[r] = bv;
  for (int k = 0; k < K; ++k) {
    float w = W[(size_t)o * K + k];
#pragma unroll
    for (int r = 0; r < 16; ++r) acc[r] = fmaf(lin[r * K + k], w, acc[r]);
  }
#pragma unroll
  for (int r = 0; r < 16; ++r) {
    float v = acc[r];
    if (act) v = geluf_(v);
    out[(size_t)r * Nout + o] = v;
  }
}

// L2 normalize rows of e[16][512]
__global__ __launch_bounds__(256) void k_norm(const float* __restrict__ e, float* __restrict__ out) {
  __shared__ float sc[4];
  int b = blockIdx.x, tid = threadIdx.x;
  float v0 = e[(size_t)b * 512 + tid], v1 = e[(size_t)b * 512 + 256 + tid];
  float ss = red256(v0 * v0 + v1 * v1, tid, sc);
  float nrm = fmaxf(sqrtf(ss), 1e-12f);
  out[(size_t)b * 512 + tid] = v0 / nrm;
  out[(size_t)b * 512 + 256 + tid] = v1 / nrm;
}

// ---------------- launch ----------------

extern "C" void kernel_launch(void* const* d_in, const int* in_sizes, int n_in,
                              void* d_out, int out_size, void* d_ws, size_t ws_size,
                              hipStream_t stream) {
  const float* x         = (const float*)d_in[0];
  const int*   lengths   = (const int*)d_in[1];
  const float* conv1_w   = (const float*)d_in[2];
  const float* bn1_w     = (const float*)d_in[3];
  const float* bn1_b     = (const float*)d_in[4];
  const float* conv2_w   = (const float*)d_in[5];
  const float* bn2_w     = (const float*)d_in[6];
  const float* bn2_b     = (const float*)d_in[7];
  const float* fproj_w   = (const float*)d_in[8];
  const float* fproj_b   = (const float*)d_in[9];
  const float* pre_ln_w  = (const float*)d_in[10];
  const float* pre_ln_b  = (const float*)d_in[11];
  const float* in_w      = (const float*)d_in[12];
  const float* in_b      = (const float*)d_in[13];
  const float* conv_w    = (const float*)d_in[14];
  const float* conv_b    = (const float*)d_in[15];
  const float* A         = (const float*)d_in[16];
  const float* Bm        = (const float*)d_in[17];
  const float* out_w     = (const float*)d_in[18];
  const float* out_b     = (const float*)d_in[19];
  const float* post_ln_w = (const float*)d_in[20];
  const float* post_ln_b = (const float*)d_in[21];
  const float* m1_w      = (const float*)d_in[22];
  const float* m1_b      = (const float*)d_in[23];
  const float* m2_w      = (const float*)d_in[24];
  const float* m2_b      = (const float*)d_in[25];
  const float* m3_w      = (const float*)d_in[26];
  const float* m3_b      = (const float*)d_in[27];
  float* outp = (float*)d_out;

  float* wsf = (float*)d_ws;
  size_t o = 0;
  auto F32 = [&](size_t n) { float* p = wsf + o; o += (n + 63) & ~(size_t)63; return p; };
  float* psum   = F32(1048576);
  float* psq    = F32(1048576);
  float* z2mx   = F32(1048576);
  float* z2mn   = F32(1048576);
  float* gatev  = psum;              // alias: psum..z2mn (4M floats) reused after K4
  float* s1t1   = F32(256);
  float* s2t2   = F32(256);
  unsigned short* W2B = (unsigned short*)F32(8192);   // 16384 bf16
  float* fprojT = F32(32768);
  float* inwT   = F32(1048576);
  float* outwT  = F32(524288);
  float* seqA   = F32(2097152);
  float* seqB   = F32(2097152);
  float* updv   = F32(4194304);
  float* uv     = F32(4194304);
  float* buv    = F32(131072);
  float* hstv   = F32(131072);
  float* pooled = F32(4096);
  float* e1     = F32(16384);
  float* e2     = F32(16384);
  float* e3     = F32(8192);
  if (ws_size < o * sizeof(float)) return;  // insufficient scratch (loud failure)

  const float invM = 1.f / (float)(NFRM * NPT);

  k_prep<<<6336, 256, 0, stream>>>(conv2_w, fproj_w, in_w, out_w, W2B, fprojT, inwT, outwT);
  k1_bn1<<<NFRM, 256, 0, stream>>>(x, conv1_w, psum, psq);
  k_red<<<CH, 256, 0, stream>>>(psum, psq, bn1_w, bn1_b, s1t1, invM, 1e-5f);
  k2_main<<<NFRM, 256, 0, stream>>>(x, conv1_w, s1t1, W2B, z2mx, z2mn, psum, psq);
  k_red<<<CH, 256, 0, stream>>>(psum, psq, bn2_w, bn2_b, s2t2, invM, 1e-5f);
  k4_feat<<<NFRM / 8, 256, 0, stream>>>(z2mx, z2mn, s2t2, fprojT, fproj_b, pre_ln_w, pre_ln_b, seqA);

  for (int l = 0; l < NL; ++l) {
    const float* sin = (l & 1) ? seqB : seqA;
    float* sout      = (l & 1) ? seqA : seqB;
    k_in<<<NFRM / 16, 256, 0, stream>>>(sin, inwT + (size_t)l * 262144, in_b + l * 1024, gatev, updv);
    k_conv<<<NFRM * HH / 256, 256, 0, stream>>>(updv, conv_w + l * 2048, conv_b + l * 512, uv);
    k_bu<<<NFRM / 16, 256, 0, stream>>>(uv, Bm + l * 8192, lengths, buv);
    k_scan<<<16, 256, 0, stream>>>(buv, hstv);
    k_out<<<NFRM / 16, 256, 0, stream>>>(hstv, gatev, A + l * 8192, outwT + (size_t)l * 131072,
                                         out_b + l * 256, lengths, sout);
  }
  // after 4 layers seq is in seqA
  k_postln<<<NFRM, 256, 0, stream>>>(seqA, post_ln_w, post_ln_b, seqB);
  k_pool<<<16, 256, 0, stream>>>(seqB, lengths, pooled);
  k_mlp<<<4, 256, 0, stream>>>(pooled, m1_w, m1_b, e1, 256, 1024, 1);
  k_mlp<<<4, 256, 0, stream>>>(e1, m2_w, m2_b, e2, 1024, 1024, 1);
  k_mlp<<<2, 256, 0, stream>>>(e2, m3_w, m3_b, e3, 1024, 512, 0);
  k_norm<<<16, 256, 0, stream>>>(e3, outp);
}

// Round 3
// 955.047 us; speedup vs baseline: 2.1591x; 1.3835x over previous
//
#include <hip/hip_runtime.h>
#include <math.h>

#define NFRM 8192   // B*T
#define NPT  128    // N points
#define CH   128    // HID
#define DD   256    // D
#define HH   512    // H
#define SS   16     // S
#define NL   4

typedef __attribute__((ext_vector_type(8))) short bf16x8;
typedef __attribute__((ext_vector_type(4))) float f32x4;
typedef unsigned short u16;

#define MFMA16 __builtin_amdgcn_mfma_f32_16x16x32_bf16

// ---------------- helpers ----------------

__device__ __forceinline__ float red256(float v, int tid, volatile float* sc) {
#pragma unroll
  for (int off = 32; off; off >>= 1) v += __shfl_down(v, off);
  __syncthreads();
  if ((tid & 63) == 0) sc[tid >> 6] = v;
  __syncthreads();
  return sc[0] + sc[1] + sc[2] + sc[3];
}

__device__ __forceinline__ float sigmoidf_(float x) { return 1.f / (1.f + expf(-x)); }
__device__ __forceinline__ float geluf_(float x) { return 0.5f * x * (1.f + erff(x * 0.70710678118654752f)); }

// round-to-nearest-even f32 -> bf16 bits
__device__ __forceinline__ u16 f2bf(float f) {
  union { float f; unsigned int u; } v; v.f = f;
  unsigned int r = v.u + 0x7FFFu + ((v.u >> 16) & 1u);
  return (u16)(r >> 16);
}
__device__ __forceinline__ float bf2f(u16 u) {
  union { unsigned int i; float f; } v; v.i = ((unsigned int)u) << 16; return v.f;
}

// ---------------- kernels ----------------

// pack weights: W2B bf16 swizzled; fprojT f32; inwB/outwB flat bf16 cast; albB zero-padded; BmT transposed
__global__ __launch_bounds__(256) void k_prep(const float* __restrict__ conv2_w,
    const float* __restrict__ fproj_w, const float* __restrict__ in_w, const float* __restrict__ out_w,
    const float* __restrict__ A, const float* __restrict__ Bm,
    u16* __restrict__ W2B, float* __restrict__ fprojT, u16* __restrict__ inwB,
    u16* __restrict__ outwB, u16* __restrict__ albB, u16* __restrict__ BmT) {
  int idx = blockIdx.x * 256 + threadIdx.x;
  if (idx < 16384) {
    int c = idx >> 7, k = idx & 127;
    int dst = c * 128 + ((((k >> 3) ^ (c & 7)) << 3) | (k & 7));
    W2B[dst] = f2bf(conv2_w[idx]);
    return;
  }
  idx -= 16384;
  if (idx < 32768) { int c = idx >> 8, d = idx & 255; fprojT[idx] = fproj_w[d * 128 + c]; return; }
  idx -= 32768;
  if (idx < 1048576) { inwB[idx] = f2bf(in_w[idx]); return; }
  idx -= 1048576;
  if (idx < 524288) { outwB[idx] = f2bf(out_w[idx]); return; }
  idx -= 524288;
  if (idx < 65536) {
    int l = idx >> 14, rem = idx & 16383, h = rem >> 5, kk = rem & 31;
    albB[idx] = (kk < 16) ? f2bf(A[(size_t)l * 8192 + h * 16 + kk]) : (u16)0;
    return;
  }
  idx -= 65536;
  if (idx < 32768) {
    int l = idx >> 13, rem = idx & 8191, s = rem >> 9, h = rem & 511;
    BmT[idx] = f2bf(Bm[(size_t)l * 8192 + h * 16 + s]);
  }
}

// per-frame 3x3 second moment of normalized points (one wave per frame)
__global__ __launch_bounds__(256) void k_mom(const float* __restrict__ x, float* __restrict__ mom) {
  int tid = threadIdx.x, lane = tid & 63, w = tid >> 6;
  int f = blockIdx.x * 4 + w;
  const float* xf = x + (size_t)f * 384 + lane * 6;
  float a0 = xf[0], a1 = xf[1], a2 = xf[2], b0 = xf[3], b1 = xf[4], b2 = xf[5];
  float s0 = a0 + b0, s1 = a1 + b1, s2 = a2 + b2;
  float p00 = a0*a0 + b0*b0, p01 = a0*a1 + b0*b1, p02 = a0*a2 + b0*b2;
  float p11 = a1*a1 + b1*b1, p12 = a1*a2 + b1*b2, p22 = a2*a2 + b2*b2;
#pragma unroll
  for (int off = 32; off; off >>= 1) {
    s0 += __shfl_down(s0, off); s1 += __shfl_down(s1, off); s2 += __shfl_down(s2, off);
    p00 += __shfl_down(p00, off); p01 += __shfl_down(p01, off); p02 += __shfl_down(p02, off);
    p11 += __shfl_down(p11, off); p12 += __shfl_down(p12, off); p22 += __shfl_down(p22, off);
  }
  if (lane == 0) {
    float mu0 = s0 * (1.f/128.f), mu1 = s1 * (1.f/128.f), mu2 = s2 * (1.f/128.f);
    float C00 = p00 - 128.f*mu0*mu0, C01 = p01 - 128.f*mu0*mu1, C02 = p02 - 128.f*mu0*mu2;
    float C11 = p11 - 128.f*mu1*mu1, C12 = p12 - 128.f*mu1*mu2, C22 = p22 - 128.f*mu2*mu2;
    float sd0 = sqrtf(C00 * (1.f/127.f)) + 1e-10f;
    float sd1 = sqrtf(C11 * (1.f/127.f)) + 1e-10f;
    float sd2 = sqrtf(C22 * (1.f/127.f)) + 1e-10f;
    float* m = mom + (size_t)f * 8;
    m[0] = C00/(sd0*sd0); m[1] = C01/(sd0*sd1); m[2] = C02/(sd0*sd2);
    m[3] = C11/(sd1*sd1); m[4] = C12/(sd1*sd2); m[5] = C22/(sd2*sd2);
  }
}

// reduce moments -> bn1 folded channel constants cc[c] = (s*w0, s*w1, s*w2, t)   (mean(z1)==0)
__global__ __launch_bounds__(256) void k_stats(const float* __restrict__ mom, const float* __restrict__ w1,
    const float* __restrict__ bw, const float* __restrict__ bb, float* __restrict__ cc) {
  __shared__ float part[32][8];
  __shared__ float Mt[6];
  int tid = threadIdx.x;
  int j = tid & 7, g = tid >> 3;
  float sm = 0.f;
  if (j < 6) for (int f = g; f < NFRM; f += 32) sm += mom[(size_t)f * 8 + j];
  part[g][j] = sm;
  __syncthreads();
  if (tid < 6) { float tot = 0.f; for (int g2 = 0; g2 < 32; ++g2) tot += part[g2][tid]; Mt[tid] = tot; }
  __syncthreads();
  if (tid < 128) {
    float w0 = w1[tid*3], wa = w1[tid*3+1], wb = w1[tid*3+2];
    float var = (w0*w0*Mt[0] + wa*wa*Mt[3] + wb*wb*Mt[5]
               + 2.f*(w0*wa*Mt[1] + w0*wb*Mt[2] + wa*wb*Mt[4])) * (1.f/1048576.f);
    float s = bw[tid] / sqrtf(var + 1e-5f);
    ((float4*)cc)[tid] = make_float4(s*w0, s*wa, s*wb, bb[tid]);
  }
}

// main fused kernel: normalize -> h1 in REGISTERS (bf16 A-frags) -> z2 via MFMA vs LDS-staged W2
// emit per-frame per-channel max/min + bn2 partial sum/sumsq
__global__ __launch_bounds__(256) void k2_main(const float* __restrict__ x, const float4* __restrict__ cc,
    const u16* __restrict__ W2B,
    float* __restrict__ z2mx, float* __restrict__ z2mn,
    float* __restrict__ psum, float* __restrict__ psq) {
  __shared__ alignas(16) u16 w2s[16384];     // 32KB, pre-swizzled
  __shared__ float4 ccs[128];
  __shared__ alignas(16) float xns[128][4];
  __shared__ float prt[2][4];
  __shared__ float smx[4][CH], smn[4][CH], ssm[4][CH], ssq[4][CH];
  int f = blockIdx.x, tid = threadIdx.x;
  const float* xf = x + (size_t)f * 384;
  for (int i = tid; i < 2048; i += 256) ((float4*)w2s)[i] = ((const float4*)W2B)[i];
  if (tid < 128) ccs[tid] = cc[tid];
  for (int i = tid; i < 384; i += 256) xns[i / 3][i % 3] = xf[i];
  __syncthreads();
  int lane = tid & 63, w = tid >> 6;
  // normalize points: threads 0-127 hold one point each; 2-wave shfl reduce
  float v0 = 0.f, v1 = 0.f, v2 = 0.f;
  if (tid < 128) { v0 = xns[tid][0]; v1 = xns[tid][1]; v2 = xns[tid][2]; }
  {
    float s0 = v0, s1 = v1, s2 = v2;
#pragma unroll
    for (int off = 32; off; off >>= 1) {
      s0 += __shfl_down(s0, off); s1 += __shfl_down(s1, off); s2 += __shfl_down(s2, off);
    }
    if (w < 2 && lane == 0) { prt[w][0] = s0; prt[w][1] = s1; prt[w][2] = s2; }
  }
  __syncthreads();
  float mu0 = (prt[0][0] + prt[1][0]) * (1.f/128.f);
  float mu1 = (prt[0][1] + prt[1][1]) * (1.f/128.f);
  float mu2 = (prt[0][2] + prt[1][2]) * (1.f/128.f);
  float d0 = v0 - mu0, d1 = v1 - mu1, d2 = v2 - mu2;
  __syncthreads();
  {
    float q0 = d0*d0, q1 = d1*d1, q2 = d2*d2;
    if (tid >= 128) { q0 = q1 = q2 = 0.f; }
#pragma unroll
    for (int off = 32; off; off >>= 1) {
      q0 += __shfl_down(q0, off); q1 += __shfl_down(q1, off); q2 += __shfl_down(q2, off);
    }
    if (w < 2 && lane == 0) { prt[w][0] = q0; prt[w][1] = q1; prt[w][2] = q2; }
  }
  __syncthreads();
  if (tid < 128) {
    float sd0 = sqrtf((prt[0][0] + prt[1][0]) * (1.f/127.f)) + 1e-10f;
    float sd1 = sqrtf((prt[0][1] + prt[1][1]) * (1.f/127.f)) + 1e-10f;
    float sd2 = sqrtf((prt[0][2] + prt[1][2]) * (1.f/127.f)) + 1e-10f;
    xns[tid][0] = d0 / sd0; xns[tid][1] = d1 / sd1; xns[tid][2] = d2 / sd2;
  }
  __syncthreads();
  // GEMM: wave w rows [w*32, w*32+32) x cols [0,128)
  int lr = lane & 15, kg = lane >> 4;
  int row0 = w * 32 + lr, row1 = w * 32 + 16 + lr;
  float4 xa = *(const float4*)&xns[row0][0];
  float4 xb = *(const float4*)&xns[row1][0];
  f32x4 acc[2][8];
#pragma unroll
  for (int fr = 0; fr < 2; ++fr)
#pragma unroll
    for (int fc = 0; fc < 8; ++fc) acc[fr][fc] = (f32x4){0.f, 0.f, 0.f, 0.f};
#pragma unroll
  for (int ks = 0; ks < 4; ++ks) {
    int kc = ks * 4 + kg, c0 = kc * 8;
    bf16x8 a0, a1;
#pragma unroll
    for (int q = 0; q < 8; ++q) {
      float4 c4 = ccs[c0 + q];
      float h0 = fmaxf(0.f, fmaf(xa.x, c4.x, fmaf(xa.y, c4.y, fmaf(xa.z, c4.z, c4.w))));
      float h1 = fmaxf(0.f, fmaf(xb.x, c4.x, fmaf(xb.y, c4.y, fmaf(xb.z, c4.z, c4.w))));
      a0[q] = (short)f2bf(h0); a1[q] = (short)f2bf(h1);
    }
#pragma unroll
    for (int fc = 0; fc < 8; ++fc) {
      int col = fc * 16 + lr;
      bf16x8 b = *(const bf16x8*)&w2s[col * 128 + ((kc ^ (col & 7)) << 3)];
      acc[0][fc] = MFMA16(a0, b, acc[0][fc], 0, 0, 0);
      acc[1][fc] = MFMA16(a1, b, acc[1][fc], 0, 0, 0);
    }
  }
  // per-channel stats
#pragma unroll
  for (int fc = 0; fc < 8; ++fc) {
    float mx = -3e38f, mn = 3e38f, sm = 0.f, sq = 0.f;
#pragma unroll
    for (int fr = 0; fr < 2; ++fr)
#pragma unroll
      for (int r = 0; r < 4; ++r) {
        float v = acc[fr][fc][r];
        mx = fmaxf(mx, v); mn = fminf(mn, v); sm += v; sq = fmaf(v, v, sq);
      }
#pragma unroll
    for (int off = 16; off <= 32; off <<= 1) {
      mx = fmaxf(mx, __shfl_xor(mx, off));
      mn = fminf(mn, __shfl_xor(mn, off));
      sm += __shfl_xor(sm, off);
      sq += __shfl_xor(sq, off);
    }
    if (lane < 16) {
      int col = fc * 16 + lr;
      smx[w][col] = mx; smn[w][col] = mn; ssm[w][col] = sm; ssq[w][col] = sq;
    }
  }
  __syncthreads();
  if (tid < CH) {
    float mx = smx[0][tid], mn = smn[0][tid], sm = ssm[0][tid], sq = ssq[0][tid];
#pragma unroll
    for (int w2 = 1; w2 < 4; ++w2) {
      mx = fmaxf(mx, smx[w2][tid]); mn = fminf(mn, smn[w2][tid]);
      sm += ssm[w2][tid]; sq += ssq[w2][tid];
    }
    z2mx[(size_t)f * CH + tid] = mx;
    z2mn[(size_t)f * CH + tid] = mn;
    psum[(size_t)f * CH + tid] = sm;
    psq[(size_t)f * CH + tid]  = sq;
  }
}

// reduce partials -> BN scale/shift (bn2)
__global__ __launch_bounds__(256) void k_red(const float* __restrict__ psum, const float* __restrict__ psq,
    const float* __restrict__ w, const float* __restrict__ b, float* __restrict__ st,
    float invM, float eps) {
  __shared__ float sc[4];
  int c = blockIdx.x, tid = threadIdx.x;
  float sm = 0.f, sq = 0.f;
  for (int f = tid; f < NFRM; f += 256) { sm += psum[(size_t)f * CH + c]; sq += psq[(size_t)f * CH + c]; }
  sm = red256(sm, tid, sc);
  sq = red256(sq, tid, sc);
  if (tid == 0) {
    float mean = sm * invM;
    float var = sq * invM - mean * mean;
    float s = w[c] / sqrtf(var + eps);
    st[c] = s;
    st[CH + c] = b[c] - mean * s;
  }
}

// feat = relu(bn2(z2ext)) @ fprojT + b ; pre-LN -> seq   (8 frames / block)
__global__ __launch_bounds__(256) void k4_feat(const float* __restrict__ z2mx, const float* __restrict__ z2mn,
    const float* __restrict__ s2t2, const float* __restrict__ fprojT, const float* __restrict__ fpb,
    const float* __restrict__ plw, const float* __restrict__ plb, float* __restrict__ seq) {
  __shared__ float h2[8][CH];
  __shared__ float sc[4];
  int f0 = blockIdx.x * 8, tid = threadIdx.x;
  for (int i = tid; i < 8 * CH; i += 256) {
    int r = i >> 7, c = i & 127;
    float s = s2t2[c], t = s2t2[CH + c];
    float z = (s >= 0.f) ? z2mx[(size_t)(f0 + r) * CH + c] : z2mn[(size_t)(f0 + r) * CH + c];
    h2[r][c] = fmaxf(0.f, fmaf(s, z, t));
  }
  __syncthreads();
  int d = tid;
  float acc[8];
  float bias = fpb[d];
#pragma unroll
  for (int r = 0; r < 8; ++r) acc[r] = bias;
  for (int c = 0; c < CH; ++c) {
    float w = fprojT[c * DD + d];
#pragma unroll
    for (int r = 0; r < 8; ++r) acc[r] = fmaf(h2[r][c], w, acc[r]);
  }
#pragma unroll
  for (int r = 0; r < 8; ++r) {
    float mu = red256(acc[r], tid, sc) * (1.f / 256.f);
    float dd = acc[r] - mu;
    float var = red256(dd * dd, tid, sc) * (1.f / 256.f);
    float rs = 1.f / sqrtf(var + 1e-5f);
    seq[(size_t)(f0 + r) * DD + d] = fmaf(dd * rs, plw[d], plb[d]);
  }
}

// in-proj via MFMA: 32 frames x 1024 cols, 8 waves; gate/upd out bf16
__global__ __launch_bounds__(512) void k_in(const float* __restrict__ seq, const u16* __restrict__ inwB_l,
    const float* __restrict__ inb, u16* __restrict__ gate, u16* __restrict__ upd) {
  __shared__ alignas(16) u16 as[32 * 256];   // 16KB bf16, chunk-XOR swizzled
  int f0 = blockIdx.x * 32, tid = threadIdx.x;
  for (int c = tid; c < 1024; c += 512) {
    int row = c >> 5, cc = c & 31;
    const float* src = seq + (size_t)(f0 + row) * 256 + cc * 8;
    float4 u0 = *(const float4*)src, u1 = *(const float4*)(src + 4);
    bf16x8 v;
    v[0] = (short)f2bf(u0.x); v[1] = (short)f2bf(u0.y); v[2] = (short)f2bf(u0.z); v[3] = (short)f2bf(u0.w);
    v[4] = (short)f2bf(u1.x); v[5] = (short)f2bf(u1.y); v[6] = (short)f2bf(u1.z); v[7] = (short)f2bf(u1.w);
    *(bf16x8*)&as[row * 256 + ((cc ^ (row & 7)) << 3)] = v;
  }
  __syncthreads();
  int lane = tid & 63, w = tid >> 6;
  int lr = lane & 15, kg = lane >> 4;
  int colb = w * 128;
  f32x4 acc[2][8];
#pragma unroll
  for (int fr = 0; fr < 2; ++fr)
#pragma unroll
    for (int fc = 0; fc < 8; ++fc) acc[fr][fc] = (f32x4){0.f, 0.f, 0.f, 0.f};
#pragma unroll
  for (int ks = 0; ks < 8; ++ks) {
    int kc = ks * 4 + kg;
    int r1 = 16 + lr;
    bf16x8 a0 = *(const bf16x8*)&as[lr * 256 + ((kc ^ (lr & 7)) << 3)];
    bf16x8 a1 = *(const bf16x8*)&as[r1 * 256 + ((kc ^ (r1 & 7)) << 3)];
#pragma unroll
    for (int fc = 0; fc < 8; ++fc) {
      int col = colb + fc * 16 + lr;
      bf16x8 b = *(const bf16x8*)&inwB_l[(size_t)col * 256 + kc * 8];
      acc[0][fc] = MFMA16(a0, b, acc[0][fc], 0, 0, 0);
      acc[1][fc] = MFMA16(a1, b, acc[1][fc], 0, 0, 0);
    }
  }
  bool isGate = (w < 4);
  u16* dst = isGate ? gate : upd;
  int cbOff = isGate ? 0 : 512;
#pragma unroll
  for (int fr = 0; fr < 2; ++fr)
#pragma unroll
    for (int fc = 0; fc < 8; ++fc) {
      int cg = colb + fc * 16 + (lane & 15);
      float bias = inb[cg];
      int colOut = cg - cbOff;
#pragma unroll
      for (int r = 0; r < 4; ++r) {
        int frame = f0 + fr * 16 + (lane >> 4) * 4 + r;
        float v = acc[fr][fc][r] + bias;
        float sg = sigmoidf_(v);
        v = isGate ? sg : v * sg;
        dst[(size_t)frame * 512 + colOut] = f2bf(v);
      }
    }
}

// depthwise conv along T, kernel 4, pad(2,2) crop :T  (bf16 in/out)
__global__ __launch_bounds__(256) void k_conv(const u16* __restrict__ updB, const float* __restrict__ cw,
    const float* __restrict__ cb, u16* __restrict__ uB) {
  int idx = blockIdx.x * 256 + threadIdx.x;    // NFRM*HH
  int h = idx & 511, f = idx >> 9;
  int t = f & 511;
  const u16* base = updB + (size_t)(f - t) * 512 + h;
  float4 cw4 = ((const float4*)cw)[h];
  float v = cb[h];
  if (t >= 2) v = fmaf(cw4.x, bf2f(base[(t - 2) * 512]), v);
  if (t >= 1) v = fmaf(cw4.y, bf2f(base[(t - 1) * 512]), v);
  v = fmaf(cw4.z, bf2f(base[t * 512]), v);
  if (t < 511) v = fmaf(cw4.w, bf2f(base[(t + 1) * 512]), v);
  uB[idx] = f2bf(v);
}

// Bu = u @ Bm (masked) via MFMA: wave = 16 frames, block = 64 frames
__global__ __launch_bounds__(256) void k_bu(const u16* __restrict__ uB, const u16* __restrict__ BmT_l,
    const int* __restrict__ lengths, float* __restrict__ bu) {
  int tid = threadIdx.x, lane = tid & 63, w = tid >> 6;
  int f0 = blockIdx.x * 64 + w * 16;
  int lr = lane & 15, kg = lane >> 4;
  f32x4 acc = (f32x4){0.f, 0.f, 0.f, 0.f};
#pragma unroll
  for (int ks = 0; ks < 16; ++ks) {
    int kc = ks * 4 + kg;
    bf16x8 a = *(const bf16x8*)&uB[(size_t)(f0 + lr) * 512 + kc * 8];
    bf16x8 b = *(const bf16x8*)&BmT_l[lr * 512 + kc * 8];
    acc = MFMA16(a, b, acc, 0, 0, 0);
  }
  int s = lane & 15;
#pragma unroll
  for (int r = 0; r < 4; ++r) {
    int frame = f0 + (lane >> 4) * 4 + r;
    int t = frame & 511, bi = frame >> 9;
    bu[(size_t)frame * 16 + s] = (t < lengths[bi]) ? acc[r] : 0.f;
  }
}

// cumsum over t per (b,s): chunked scan in LDS with conflict-break padding
#define SIDX(t, s) ((t) * 16 + (s) + (((t) >> 5) << 3))
__global__ __launch_bounds__(256) void k_scan(const float* __restrict__ bu, float* __restrict__ hst) {
  __shared__ float buf[8320];
  __shared__ float tot[16][SS];
  int b = blockIdx.x, tid = threadIdx.x;
  for (int i = tid; i < 8192; i += 256) { int t = i >> 4, s = i & 15; buf[SIDX(t, s)] = bu[(size_t)b * 8192 + i]; }
  __syncthreads();
  int s = tid & 15, ck = tid >> 4;
  int base = ck * 32;
  float acc = 0.f;
  for (int i = 0; i < 32; ++i) { acc += buf[SIDX(base + i, s)]; buf[SIDX(base + i, s)] = acc; }
  tot[ck][s] = acc;
  __syncthreads();
  float off = 0.f;
  for (int c2 = 0; c2 < 16; ++c2) if (c2 < ck) off += tot[c2][s];
  for (int i = 0; i < 32; ++i) buf[SIDX(base + i, s)] += off;
  __syncthreads();
  for (int i = tid; i < 8192; i += 256) { int t = i >> 4, s2 = i & 15; hst[(size_t)b * 8192 + i] = buf[SIDX(t, s2)]; }
}

// out-proj: phase A V=(hs@A^T)*gate*mask via K=32 MFMA; phase B sout = V @ out_w^T + b via MFMA
__global__ __launch_bounds__(256) void k_out(const float* __restrict__ hst, const u16* __restrict__ gateB,
    const u16* __restrict__ albB_l, const u16* __restrict__ outwB_l, const float* __restrict__ outb,
    const int* __restrict__ lengths, float* __restrict__ sout) {
  __shared__ alignas(16) u16 hsb[32 * 40];    // stride 40 shorts (80B, 16B-aligned)
  __shared__ alignas(16) u16 vl[32 * 512];    // 32KB V bf16, chunk-XOR swizzled
  int f0 = blockIdx.x * 32, tid = threadIdx.x;
  int len = lengths[f0 >> 9];
  for (int i = tid; i < 512; i += 256) {
    int row = i >> 4, s = i & 15;
    hsb[row * 40 + s] = f2bf(hst[(size_t)(f0 + row) * 16 + s]);
    hsb[row * 40 + 16 + s] = 0;
  }
  __syncthreads();
  int lane = tid & 63, w = tid >> 6, lr = lane & 15, kg = lane >> 4;
  {
    bf16x8 a0 = *(const bf16x8*)&hsb[lr * 40 + kg * 8];
    bf16x8 a1 = *(const bf16x8*)&hsb[(16 + lr) * 40 + kg * 8];
    f32x4 zero = (f32x4){0.f, 0.f, 0.f, 0.f};
#pragma unroll
    for (int fc = 0; fc < 8; ++fc) {
      int h = w * 128 + fc * 16 + lr;
      bf16x8 b = *(const bf16x8*)&albB_l[h * 32 + kg * 8];
      f32x4 va = MFMA16(a0, b, zero, 0, 0, 0);
      f32x4 vb = MFMA16(a1, b, zero, 0, 0, 0);
      int hck = h >> 3, hlo = h & 7;
#pragma unroll
      for (int fr = 0; fr < 2; ++fr) {
        f32x4 vv = fr ? vb : va;
#pragma unroll
        for (int r = 0; r < 4; ++r) {
          int fl = fr * 16 + (lane >> 4) * 4 + r;
          int frame = f0 + fl;
          float g = bf2f(gateB[(size_t)frame * 512 + h]);
          float val = ((frame & 511) < len) ? vv[r] * g : 0.f;
          vl[fl * 512 + ((hck ^ (fl & 7)) << 3) + hlo] = f2bf(val);
        }
      }
    }
  }
  __syncthreads();
  f32x4 acc[2][4];
#pragma unroll
  for (int fr = 0; fr < 2; ++fr)
#pragma unroll
    for (int fc = 0; fc < 4; ++fc) acc[fr][fc] = (f32x4){0.f, 0.f, 0.f, 0.f};
  int db = w * 64;
#pragma unroll
  for (int ks = 0; ks < 16; ++ks) {
    int kc = ks * 4 + kg;
    int r1 = 16 + lr;
    bf16x8 a0 = *(const bf16x8*)&vl[lr * 512 + ((kc ^ (lr & 7)) << 3)];
    bf16x8 a1 = *(const bf16x8*)&vl[r1 * 512 + ((kc ^ (r1 & 7)) << 3)];
#pragma unroll
    for (int fc = 0; fc < 4; ++fc) {
      int d = db + fc * 16 + lr;
      bf16x8 b = *(const bf16x8*)&outwB_l[(size_t)d * 512 + kc * 8];
      acc[0][fc] = MFMA16(a0, b, acc[0][fc], 0, 0, 0);
      acc[1][fc] = MFMA16(a1, b, acc[1][fc], 0, 0, 0);
    }
  }
#pragma unroll
  for (int fr = 0; fr < 2; ++fr)
#pragma unroll
    for (int fc = 0; fc < 4; ++fc) {
      int d = db + fc * 16 + (lane & 15);
      float bias = outb[d];
#pragma unroll
      for (int r = 0; r < 4; ++r) {
        int frame = f0 + fr * 16 + (lane >> 4) * 4 + r;
        sout[(size_t)frame * 256 + d] = acc[fr][fc][r] + bias;
      }
    }
}

// post-LN per frame
__global__ __launch_bounds__(256) void k_postln(const float* __restrict__ seq, const float* __restrict__ w,
    const float* __restrict__ b, float* __restrict__ out) {
  __shared__ float sc[4];
  int f = blockIdx.x, tid = threadIdx.x;
  float v = seq[(size_t)f * DD + tid];
  float mu = red256(v, tid, sc) * (1.f / 256.f);
  float dd = v - mu;
  float var = red256(dd * dd, tid, sc) * (1.f / 256.f);
  float rs = 1.f / sqrtf(var + 1e-5f);
  out[(size_t)f * DD + tid] = fmaf(dd * rs, w[tid], b[tid]);
}

// masked mean pool over t (one block per b)
__global__ __launch_bounds__(256) void k_pool(const float* __restrict__ lnseq, const int* __restrict__ lengths,
    float* __restrict__ pooled) {
  int b = blockIdx.x, d = threadIdx.x;
  int len = lengths[b];
  float acc = 0.f;
  for (int t = 0; t < len; ++t) acc += lnseq[((size_t)b * 512 + t) * DD + d];
  pooled[b * DD + d] = acc / (float)max(len, 1);
}

// 16-row MLP layer: out[16][Nout] = act(in[16][K] @ W^T + b)
__global__ __launch_bounds__(256) void k_mlp(const float* __restrict__ in, const float* __restrict__ W,
    const float* __restrict__ bias, float* __restrict__ out, int K, int Nout, int act) {
  __shared__ float lin[16 * 1024];
  int tid = threadIdx.x;
  for (int i = tid; i < 16 * K; i += 256) lin[i] = in[i];
  __syncthreads();
  int o = blockIdx.x * 256 + tid;
  float acc[16];
  float bv = bias[o];
#pragma unroll
  for (int r = 0; r < 16; ++r) acc[r] = bv;
  for (int k = 0; k < K; ++k) {
    float w = W[(size_t)o * K + k];
#pragma unroll
    for (int r = 0; r < 16; ++r) acc[r] = fmaf(lin[r * K + k], w, acc[r]);
  }
#pragma unroll
  for (int r = 0; r < 16; ++r) {
    float v = acc[r];
    if (act) v = geluf_(v);
    out[(size_t)r * Nout + o] = v;
  }
}

// L2 normalize rows of e[16][512]
__global__ __launch_bounds__(256) void k_norm(const float* __restrict__ e, float* __restrict__ out) {
  __shared__ float sc[4];
  int b = blockIdx.x, tid = threadIdx.x;
  float v0 = e[(size_t)b * 512 + tid], v1 = e[(size_t)b * 512 + 256 + tid];
  float ss = red256(v0 * v0 + v1 * v1, tid, sc);
  float nrm = fmaxf(sqrtf(ss), 1e-12f);
  out[(size_t)b * 512 + tid] = v0 / nrm;
  out[(size_t)b * 512 + 256 + tid] = v1 / nrm;
}

// ---------------- launch ----------------

extern "C" void kernel_launch(void* const* d_in, const int* in_sizes, int n_in,
                              void* d_out, int out_size, void* d_ws, size_t ws_size,
                              hipStream_t stream) {
  const float* x         = (const float*)d_in[0];
  const int*   lengths   = (const int*)d_in[1];
  const float* conv1_w   = (const float*)d_in[2];
  const float* bn1_w     = (const float*)d_in[3];
  const float* bn1_b     = (const float*)d_in[4];
  const float* conv2_w   = (const float*)d_in[5];
  const float* bn2_w     = (const float*)d_in[6];
  const float* bn2_b     = (const float*)d_in[7];
  const float* fproj_w   = (const float*)d_in[8];
  const float* fproj_b   = (const float*)d_in[9];
  const float* pre_ln_w  = (const float*)d_in[10];
  const float* pre_ln_b  = (const float*)d_in[11];
  const float* in_w      = (const float*)d_in[12];
  const float* in_b      = (const float*)d_in[13];
  const float* conv_w    = (const float*)d_in[14];
  const float* conv_b    = (const float*)d_in[15];
  const float* A         = (const float*)d_in[16];
  const float* Bm        = (const float*)d_in[17];
  const float* out_w     = (const float*)d_in[18];
  const float* out_b     = (const float*)d_in[19];
  const float* post_ln_w = (const float*)d_in[20];
  const float* post_ln_b = (const float*)d_in[21];
  const float* m1_w      = (const float*)d_in[22];
  const float* m1_b      = (const float*)d_in[23];
  const float* m2_w      = (const float*)d_in[24];
  const float* m2_b      = (const float*)d_in[25];
  const float* m3_w      = (const float*)d_in[26];
  const float* m3_b      = (const float*)d_in[27];
  float* outp = (float*)d_out;

  float* wsf = (float*)d_ws;
  size_t o = 0;
  auto F32 = [&](size_t n) { float* p = wsf + o; o += (n + 63) & ~(size_t)63; return p; };
  float* psum   = F32(1048576);
  float* psq    = F32(1048576);
  float* z2mx   = F32(1048576);
  float* z2mn   = F32(1048576);
  float* mom    = F32(65536);
  float* cc     = F32(512);
  float* s2t2   = F32(256);
  u16*   W2B    = (u16*)F32(8192);      // 16384 bf16
  float* fprojT = F32(32768);
  u16*   inwB   = (u16*)F32(524288);    // 1048576 bf16
  u16*   outwB  = (u16*)F32(262144);    // 524288 bf16
  u16*   albB   = (u16*)F32(32768);     // 65536 bf16
  u16*   BmT    = (u16*)F32(16384);     // 32768 bf16
  float* seqA   = F32(2097152);
  float* seqB   = F32(2097152);
  u16*   gateB  = (u16*)F32(2097152);   // 8192x512 bf16
  u16*   updB   = (u16*)F32(2097152);
  u16*   uB     = (u16*)F32(2097152);
  float* buv    = F32(131072);
  float* hstv   = F32(131072);
  float* pooled = F32(4096);
  float* e1     = F32(16384);
  float* e2     = F32(16384);
  float* e3     = F32(8192);
  if (ws_size < o * sizeof(float)) return;

  const float invM = 1.f / (float)(NFRM * NPT);

  k_prep<<<6720, 256, 0, stream>>>(conv2_w, fproj_w, in_w, out_w, A, Bm,
                                   W2B, fprojT, inwB, outwB, albB, BmT);
  k_mom<<<2048, 256, 0, stream>>>(x, mom);
  k_stats<<<1, 256, 0, stream>>>(mom, conv1_w, bn1_w, bn1_b, cc);
  k2_main<<<NFRM, 256, 0, stream>>>(x, (const float4*)cc, W2B, z2mx, z2mn, psum, psq);
  k_red<<<CH, 256, 0, stream>>>(psum, psq, bn2_w, bn2_b, s2t2, invM, 1e-5f);
  k4_feat<<<NFRM / 8, 256, 0, stream>>>(z2mx, z2mn, s2t2, fprojT, fproj_b, pre_ln_w, pre_ln_b, seqA);

  for (int l = 0; l < NL; ++l) {
    const float* sin = (l & 1) ? seqB : seqA;
    float* sout      = (l & 1) ? seqA : seqB;
    k_in<<<NFRM / 32, 512, 0, stream>>>(sin, inwB + (size_t)l * 262144, in_b + l * 1024, gateB, updB);
    k_conv<<<NFRM * HH / 256, 256, 0, stream>>>(updB, conv_w + l * 2048, conv_b + l * 512, uB);
    k_bu<<<NFRM / 64, 256, 0, stream>>>(uB, BmT + (size_t)l * 8192, lengths, buv);
    k_scan<<<16, 256, 0, stream>>>(buv, hstv);
    k_out<<<NFRM / 32, 256, 0, stream>>>(hstv, gateB, albB + (size_t)l * 16384,
                                         outwB + (size_t)l * 131072, out_b + l * 256, lengths, sout);
  }
  k_postln<<<NFRM, 256, 0, stream>>>(seqA, post_ln_w, post_ln_b, seqB);
  k_pool<<<16, 256, 0, stream>>>(seqB, lengths, pooled);
  k_mlp<<<4, 256, 0, stream>>>(pooled, m1_w, m1_b, e1, 256, 1024, 1);
  k_mlp<<<4, 256, 0, stream>>>(e1, m2_w, m2_b, e2, 1024, 1024, 1);
  k_mlp<<<2, 256, 0, stream>>>(e2, m3_w, m3_b, e3, 1024, 512, 0);
  k_norm<<<16, 256, 0, stream>>>(e3, outp);
}

// Round 4
// 707.427 us; speedup vs baseline: 2.9148x; 1.3500x over previous
//
#include <hip/hip_runtime.h>
#include <math.h>

#define NFRM 8192   // B*T
#define NPT  128    // N points
#define CH   128    // HID
#define DD   256    // D
#define HH   512    // H
#define SS   16     // S
#define NL   4

typedef __attribute__((ext_vector_type(8))) short bf16x8;
typedef __attribute__((ext_vector_type(4))) float f32x4;
typedef unsigned short u16;

#define MFMA16 __builtin_amdgcn_mfma_f32_16x16x32_bf16

// ---------------- helpers ----------------

__device__ __forceinline__ float red256(float v, int tid, volatile float* sc) {
#pragma unroll
  for (int off = 32; off; off >>= 1) v += __shfl_down(v, off);
  __syncthreads();
  if ((tid & 63) == 0) sc[tid >> 6] = v;
  __syncthreads();
  return sc[0] + sc[1] + sc[2] + sc[3];
}

__device__ __forceinline__ float sigmoidf_(float x) { return 1.f / (1.f + expf(-x)); }
__device__ __forceinline__ float geluf_(float x) { return 0.5f * x * (1.f + erff(x * 0.70710678118654752f)); }

// round-to-nearest-even f32 -> bf16 bits
__device__ __forceinline__ u16 f2bf(float f) {
  union { float f; unsigned int u; } v; v.f = f;
  unsigned int r = v.u + 0x7FFFu + ((v.u >> 16) & 1u);
  return (u16)(r >> 16);
}
__device__ __forceinline__ float bf2f(u16 u) {
  union { unsigned int i; float f; } v; v.i = ((unsigned int)u) << 16; return v.f;
}

// ---------------- kernels ----------------

// pack weights: W2B bf16 swizzled; fprojT f32; inwB/outwB flat bf16 cast; albB zero-padded; BmT transposed
__global__ __launch_bounds__(256) void k_prep(const float* __restrict__ conv2_w,
    const float* __restrict__ fproj_w, const float* __restrict__ in_w, const float* __restrict__ out_w,
    const float* __restrict__ A, const float* __restrict__ Bm,
    u16* __restrict__ W2B, float* __restrict__ fprojT, u16* __restrict__ inwB,
    u16* __restrict__ outwB, u16* __restrict__ albB, u16* __restrict__ BmT) {
  int idx = blockIdx.x * 256 + threadIdx.x;
  if (idx < 16384) {
    int c = idx >> 7, k = idx & 127;
    int dst = c * 128 + ((((k >> 3) ^ (c & 7)) << 3) | (k & 7));
    W2B[dst] = f2bf(conv2_w[idx]);
    return;
  }
  idx -= 16384;
  if (idx < 32768) { int c = idx >> 8, d = idx & 255; fprojT[idx] = fproj_w[d * 128 + c]; return; }
  idx -= 32768;
  if (idx < 1048576) { inwB[idx] = f2bf(in_w[idx]); return; }
  idx -= 1048576;
  if (idx < 524288) { outwB[idx] = f2bf(out_w[idx]); return; }
  idx -= 524288;
  if (idx < 65536) {
    int l = idx >> 14, rem = idx & 16383, h = rem >> 5, kk = rem & 31;
    albB[idx] = (kk < 16) ? f2bf(A[(size_t)l * 8192 + h * 16 + kk]) : (u16)0;
    return;
  }
  idx -= 65536;
  if (idx < 32768) {
    int l = idx >> 13, rem = idx & 8191, s = rem >> 9, h = rem & 511;
    BmT[idx] = f2bf(Bm[(size_t)l * 8192 + h * 16 + s]);
  }
}

// per-frame 3x3 second moment of normalized points (one wave per frame)
__global__ __launch_bounds__(256) void k_mom(const float* __restrict__ x, float* __restrict__ mom) {
  int tid = threadIdx.x, lane = tid & 63, w = tid >> 6;
  int f = blockIdx.x * 4 + w;
  const float* xf = x + (size_t)f * 384 + lane * 6;
  float a0 = xf[0], a1 = xf[1], a2 = xf[2], b0 = xf[3], b1 = xf[4], b2 = xf[5];
  float s0 = a0 + b0, s1 = a1 + b1, s2 = a2 + b2;
  float p00 = a0*a0 + b0*b0, p01 = a0*a1 + b0*b1, p02 = a0*a2 + b0*b2;
  float p11 = a1*a1 + b1*b1, p12 = a1*a2 + b1*b2, p22 = a2*a2 + b2*b2;
#pragma unroll
  for (int off = 32; off; off >>= 1) {
    s0 += __shfl_down(s0, off); s1 += __shfl_down(s1, off); s2 += __shfl_down(s2, off);
    p00 += __shfl_down(p00, off); p01 += __shfl_down(p01, off); p02 += __shfl_down(p02, off);
    p11 += __shfl_down(p11, off); p12 += __shfl_down(p12, off); p22 += __shfl_down(p22, off);
  }
  if (lane == 0) {
    float mu0 = s0 * (1.f/128.f), mu1 = s1 * (1.f/128.f), mu2 = s2 * (1.f/128.f);
    float C00 = p00 - 128.f*mu0*mu0, C01 = p01 - 128.f*mu0*mu1, C02 = p02 - 128.f*mu0*mu2;
    float C11 = p11 - 128.f*mu1*mu1, C12 = p12 - 128.f*mu1*mu2, C22 = p22 - 128.f*mu2*mu2;
    float sd0 = sqrtf(C00 * (1.f/127.f)) + 1e-10f;
    float sd1 = sqrtf(C11 * (1.f/127.f)) + 1e-10f;
    float sd2 = sqrtf(C22 * (1.f/127.f)) + 1e-10f;
    float* m = mom + (size_t)f * 8;
    m[0] = C00/(sd0*sd0); m[1] = C01/(sd0*sd1); m[2] = C02/(sd0*sd2);
    m[3] = C11/(sd1*sd1); m[4] = C12/(sd1*sd2); m[5] = C22/(sd2*sd2);
  }
}

// reduce moments -> bn1 folded channel constants cc[c] = (s*w0, s*w1, s*w2, t)   (mean(z1)==0)
__global__ __launch_bounds__(256) void k_stats(const float* __restrict__ mom, const float* __restrict__ w1,
    const float* __restrict__ bw, const float* __restrict__ bb, float* __restrict__ cc) {
  __shared__ float part[32][8];
  __shared__ float Mt[6];
  int tid = threadIdx.x;
  int j = tid & 7, g = tid >> 3;
  float sm = 0.f;
  if (j < 6) for (int f = g; f < NFRM; f += 32) sm += mom[(size_t)f * 8 + j];
  part[g][j] = sm;
  __syncthreads();
  if (tid < 6) { float tot = 0.f; for (int g2 = 0; g2 < 32; ++g2) tot += part[g2][tid]; Mt[tid] = tot; }
  __syncthreads();
  if (tid < 128) {
    float w0 = w1[tid*3], wa = w1[tid*3+1], wb = w1[tid*3+2];
    float var = (w0*w0*Mt[0] + wa*wa*Mt[3] + wb*wb*Mt[5]
               + 2.f*(w0*wa*Mt[1] + w0*wb*Mt[2] + wa*wb*Mt[4])) * (1.f/1048576.f);
    float s = bw[tid] / sqrtf(var + 1e-5f);
    ((float4*)cc)[tid] = make_float4(s*w0, s*wa, s*wb, bb[tid]);
  }
}

// main fused kernel: 4 frames per block (W2 staged once); normalize -> h1 in regs -> MFMA
__global__ __launch_bounds__(256) void k2_main(const float* __restrict__ x, const float4* __restrict__ cc,
    const u16* __restrict__ W2B,
    float* __restrict__ z2mx, float* __restrict__ z2mn,
    float* __restrict__ psum, float* __restrict__ psq) {
  __shared__ alignas(16) u16 w2s[16384];     // 32KB, pre-swizzled
  __shared__ float4 ccs[128];
  __shared__ alignas(16) float xns[128][4];
  __shared__ float prt[2][4];
  __shared__ float smx[4][CH], smn[4][CH], ssm[4][CH], ssq[4][CH];
  int tid = threadIdx.x;
  for (int i = tid; i < 2048; i += 256) ((float4*)w2s)[i] = ((const float4*)W2B)[i];
  if (tid < 128) ccs[tid] = cc[tid];
  int lane = tid & 63, w = tid >> 6;
  int lr = lane & 15, kg = lane >> 4;
  for (int fi = 0; fi < 4; ++fi) {
    int f = blockIdx.x * 4 + fi;
    const float* xf = x + (size_t)f * 384;
    __syncthreads();                         // w2s ready (fi=0) / xns,smx reuse guard
    for (int i = tid; i < 384; i += 256) xns[i / 3][i % 3] = xf[i];
    __syncthreads();
    // normalize points: threads 0-127 hold one point each; 2-wave shfl reduce
    float v0 = 0.f, v1 = 0.f, v2 = 0.f;
    if (tid < 128) { v0 = xns[tid][0]; v1 = xns[tid][1]; v2 = xns[tid][2]; }
    {
      float s0 = v0, s1 = v1, s2 = v2;
#pragma unroll
      for (int off = 32; off; off >>= 1) {
        s0 += __shfl_down(s0, off); s1 += __shfl_down(s1, off); s2 += __shfl_down(s2, off);
      }
      if (w < 2 && lane == 0) { prt[w][0] = s0; prt[w][1] = s1; prt[w][2] = s2; }
    }
    __syncthreads();
    float mu0 = (prt[0][0] + prt[1][0]) * (1.f/128.f);
    float mu1 = (prt[0][1] + prt[1][1]) * (1.f/128.f);
    float mu2 = (prt[0][2] + prt[1][2]) * (1.f/128.f);
    float d0 = v0 - mu0, d1 = v1 - mu1, d2 = v2 - mu2;
    __syncthreads();
    {
      float q0 = d0*d0, q1 = d1*d1, q2 = d2*d2;
      if (tid >= 128) { q0 = q1 = q2 = 0.f; }
#pragma unroll
      for (int off = 32; off; off >>= 1) {
        q0 += __shfl_down(q0, off); q1 += __shfl_down(q1, off); q2 += __shfl_down(q2, off);
      }
      if (w < 2 && lane == 0) { prt[w][0] = q0; prt[w][1] = q1; prt[w][2] = q2; }
    }
    __syncthreads();
    if (tid < 128) {
      float sd0 = sqrtf((prt[0][0] + prt[1][0]) * (1.f/127.f)) + 1e-10f;
      float sd1 = sqrtf((prt[0][1] + prt[1][1]) * (1.f/127.f)) + 1e-10f;
      float sd2 = sqrtf((prt[0][2] + prt[1][2]) * (1.f/127.f)) + 1e-10f;
      xns[tid][0] = d0 / sd0; xns[tid][1] = d1 / sd1; xns[tid][2] = d2 / sd2;
    }
    __syncthreads();
    // GEMM: wave w rows [w*32, w*32+32) x cols [0,128)
    int row0 = w * 32 + lr, row1 = w * 32 + 16 + lr;
    float4 xa = *(const float4*)&xns[row0][0];
    float4 xb = *(const float4*)&xns[row1][0];
    f32x4 acc[2][8];
#pragma unroll
    for (int fr = 0; fr < 2; ++fr)
#pragma unroll
      for (int fc = 0; fc < 8; ++fc) acc[fr][fc] = (f32x4){0.f, 0.f, 0.f, 0.f};
#pragma unroll
    for (int ks = 0; ks < 4; ++ks) {
      int kc = ks * 4 + kg, c0 = kc * 8;
      bf16x8 a0, a1;
#pragma unroll
      for (int q = 0; q < 8; ++q) {
        float4 c4 = ccs[c0 + q];
        float h0 = fmaxf(0.f, fmaf(xa.x, c4.x, fmaf(xa.y, c4.y, fmaf(xa.z, c4.z, c4.w))));
        float h1 = fmaxf(0.f, fmaf(xb.x, c4.x, fmaf(xb.y, c4.y, fmaf(xb.z, c4.z, c4.w))));
        a0[q] = (short)f2bf(h0); a1[q] = (short)f2bf(h1);
      }
#pragma unroll
      for (int fc = 0; fc < 8; ++fc) {
        int col = fc * 16 + lr;
        bf16x8 b = *(const bf16x8*)&w2s[col * 128 + ((kc ^ (col & 7)) << 3)];
        acc[0][fc] = MFMA16(a0, b, acc[0][fc], 0, 0, 0);
        acc[1][fc] = MFMA16(a1, b, acc[1][fc], 0, 0, 0);
      }
    }
    // per-channel stats
#pragma unroll
    for (int fc = 0; fc < 8; ++fc) {
      float mx = -3e38f, mn = 3e38f, sm = 0.f, sq = 0.f;
#pragma unroll
      for (int fr = 0; fr < 2; ++fr)
#pragma unroll
        for (int r = 0; r < 4; ++r) {
          float v = acc[fr][fc][r];
          mx = fmaxf(mx, v); mn = fminf(mn, v); sm += v; sq = fmaf(v, v, sq);
        }
#pragma unroll
      for (int off = 16; off <= 32; off <<= 1) {
        mx = fmaxf(mx, __shfl_xor(mx, off));
        mn = fminf(mn, __shfl_xor(mn, off));
        sm += __shfl_xor(sm, off);
        sq += __shfl_xor(sq, off);
      }
      if (lane < 16) {
        int col = fc * 16 + lr;
        smx[w][col] = mx; smn[w][col] = mn; ssm[w][col] = sm; ssq[w][col] = sq;
      }
    }
    __syncthreads();
    if (tid < CH) {
      float mx = smx[0][tid], mn = smn[0][tid], sm = ssm[0][tid], sq = ssq[0][tid];
#pragma unroll
      for (int w2 = 1; w2 < 4; ++w2) {
        mx = fmaxf(mx, smx[w2][tid]); mn = fminf(mn, smn[w2][tid]);
        sm += ssm[w2][tid]; sq += ssq[w2][tid];
      }
      z2mx[(size_t)f * CH + tid] = mx;
      z2mn[(size_t)f * CH + tid] = mn;
      psum[(size_t)f * CH + tid] = sm;
      psq[(size_t)f * CH + tid]  = sq;
    }
  }
}

// reduce partials -> BN scale/shift (bn2)
__global__ __launch_bounds__(256) void k_red(const float* __restrict__ psum, const float* __restrict__ psq,
    const float* __restrict__ w, const float* __restrict__ b, float* __restrict__ st,
    float invM, float eps) {
  __shared__ float sc[4];
  int c = blockIdx.x, tid = threadIdx.x;
  float sm = 0.f, sq = 0.f;
  for (int f = tid; f < NFRM; f += 256) { sm += psum[(size_t)f * CH + c]; sq += psq[(size_t)f * CH + c]; }
  sm = red256(sm, tid, sc);
  sq = red256(sq, tid, sc);
  if (tid == 0) {
    float mean = sm * invM;
    float var = sq * invM - mean * mean;
    float s = w[c] / sqrtf(var + eps);
    st[c] = s;
    st[CH + c] = b[c] - mean * s;
  }
}

// feat = relu(bn2(z2ext)) @ fprojT + b ; pre-LN -> seq   (8 frames / block)
__global__ __launch_bounds__(256) void k4_feat(const float* __restrict__ z2mx, const float* __restrict__ z2mn,
    const float* __restrict__ s2t2, const float* __restrict__ fprojT, const float* __restrict__ fpb,
    const float* __restrict__ plw, const float* __restrict__ plb, float* __restrict__ seq) {
  __shared__ float h2[8][CH];
  __shared__ float sc[4];
  int f0 = blockIdx.x * 8, tid = threadIdx.x;
  for (int i = tid; i < 8 * CH; i += 256) {
    int r = i >> 7, c = i & 127;
    float s = s2t2[c], t = s2t2[CH + c];
    float z = (s >= 0.f) ? z2mx[(size_t)(f0 + r) * CH + c] : z2mn[(size_t)(f0 + r) * CH + c];
    h2[r][c] = fmaxf(0.f, fmaf(s, z, t));
  }
  __syncthreads();
  int d = tid;
  float acc[8];
  float bias = fpb[d];
#pragma unroll
  for (int r = 0; r < 8; ++r) acc[r] = bias;
  for (int c = 0; c < CH; ++c) {
    float w = fprojT[c * DD + d];
#pragma unroll
    for (int r = 0; r < 8; ++r) acc[r] = fmaf(h2[r][c], w, acc[r]);
  }
#pragma unroll
  for (int r = 0; r < 8; ++r) {
    float mu = red256(acc[r], tid, sc) * (1.f / 256.f);
    float dd = acc[r] - mu;
    float var = red256(dd * dd, tid, sc) * (1.f / 256.f);
    float rs = 1.f / sqrtf(var + 1e-5f);
    seq[(size_t)(f0 + r) * DD + d] = fmaf(dd * rs, plw[d], plb[d]);
  }
}

// in-proj via MFMA: 32 frames x 1024 cols, 8 waves; gate/upd out bf16
__global__ __launch_bounds__(512) void k_in(const float* __restrict__ seq, const u16* __restrict__ inwB_l,
    const float* __restrict__ inb, u16* __restrict__ gate, u16* __restrict__ upd) {
  __shared__ alignas(16) u16 as[32 * 256];   // 16KB bf16, chunk-XOR swizzled
  int f0 = blockIdx.x * 32, tid = threadIdx.x;
  for (int c = tid; c < 1024; c += 512) {
    int row = c >> 5, cc = c & 31;
    const float* src = seq + (size_t)(f0 + row) * 256 + cc * 8;
    float4 u0 = *(const float4*)src, u1 = *(const float4*)(src + 4);
    bf16x8 v;
    v[0] = (short)f2bf(u0.x); v[1] = (short)f2bf(u0.y); v[2] = (short)f2bf(u0.z); v[3] = (short)f2bf(u0.w);
    v[4] = (short)f2bf(u1.x); v[5] = (short)f2bf(u1.y); v[6] = (short)f2bf(u1.z); v[7] = (short)f2bf(u1.w);
    *(bf16x8*)&as[row * 256 + ((cc ^ (row & 7)) << 3)] = v;
  }
  __syncthreads();
  int lane = tid & 63, w = tid >> 6;
  int lr = lane & 15, kg = lane >> 4;
  int colb = w * 128;
  f32x4 acc[2][8];
#pragma unroll
  for (int fr = 0; fr < 2; ++fr)
#pragma unroll
    for (int fc = 0; fc < 8; ++fc) acc[fr][fc] = (f32x4){0.f, 0.f, 0.f, 0.f};
#pragma unroll
  for (int ks = 0; ks < 8; ++ks) {
    int kc = ks * 4 + kg;
    int r1 = 16 + lr;
    bf16x8 a0 = *(const bf16x8*)&as[lr * 256 + ((kc ^ (lr & 7)) << 3)];
    bf16x8 a1 = *(const bf16x8*)&as[r1 * 256 + ((kc ^ (r1 & 7)) << 3)];
#pragma unroll
    for (int fc = 0; fc < 8; ++fc) {
      int col = colb + fc * 16 + lr;
      bf16x8 b = *(const bf16x8*)&inwB_l[(size_t)col * 256 + kc * 8];
      acc[0][fc] = MFMA16(a0, b, acc[0][fc], 0, 0, 0);
      acc[1][fc] = MFMA16(a1, b, acc[1][fc], 0, 0, 0);
    }
  }
  bool isGate = (w < 4);
  u16* dst = isGate ? gate : upd;
  int cbOff = isGate ? 0 : 512;
#pragma unroll
  for (int fr = 0; fr < 2; ++fr)
#pragma unroll
    for (int fc = 0; fc < 8; ++fc) {
      int cg = colb + fc * 16 + (lane & 15);
      float bias = inb[cg];
      int colOut = cg - cbOff;
#pragma unroll
      for (int r = 0; r < 4; ++r) {
        int frame = f0 + fr * 16 + (lane >> 4) * 4 + r;
        float v = acc[fr][fc][r] + bias;
        float sg = sigmoidf_(v);
        v = isGate ? sg : v * sg;
        dst[(size_t)frame * 512 + colOut] = f2bf(v);
      }
    }
}

// depthwise conv along T, kernel 4, pad(2,2) crop :T  (bf16 in/out)
__global__ __launch_bounds__(256) void k_conv(const u16* __restrict__ updB, const float* __restrict__ cw,
    const float* __restrict__ cb, u16* __restrict__ uB) {
  int idx = blockIdx.x * 256 + threadIdx.x;    // NFRM*HH
  int h = idx & 511, f = idx >> 9;
  int t = f & 511;
  const u16* base = updB + (size_t)(f - t) * 512 + h;
  float4 cw4 = ((const float4*)cw)[h];
  float v = cb[h];
  if (t >= 2) v = fmaf(cw4.x, bf2f(base[(t - 2) * 512]), v);
  if (t >= 1) v = fmaf(cw4.y, bf2f(base[(t - 1) * 512]), v);
  v = fmaf(cw4.z, bf2f(base[t * 512]), v);
  if (t < 511) v = fmaf(cw4.w, bf2f(base[(t + 1) * 512]), v);
  uB[idx] = f2bf(v);
}

// Bu = u @ Bm (masked) via MFMA: wave = 16 frames, block = 64 frames
__global__ __launch_bounds__(256) void k_bu(const u16* __restrict__ uB, const u16* __restrict__ BmT_l,
    const int* __restrict__ lengths, float* __restrict__ bu) {
  int tid = threadIdx.x, lane = tid & 63, w = tid >> 6;
  int f0 = blockIdx.x * 64 + w * 16;
  int lr = lane & 15, kg = lane >> 4;
  f32x4 acc = (f32x4){0.f, 0.f, 0.f, 0.f};
#pragma unroll
  for (int ks = 0; ks < 16; ++ks) {
    int kc = ks * 4 + kg;
    bf16x8 a = *(const bf16x8*)&uB[(size_t)(f0 + lr) * 512 + kc * 8];
    bf16x8 b = *(const bf16x8*)&BmT_l[lr * 512 + kc * 8];
    acc = MFMA16(a, b, acc, 0, 0, 0);
  }
  int s = lane & 15;
#pragma unroll
  for (int r = 0; r < 4; ++r) {
    int frame = f0 + (lane >> 4) * 4 + r;
    int t = frame & 511, bi = frame >> 9;
    bu[(size_t)frame * 16 + s] = (t < lengths[bi]) ? acc[r] : 0.f;
  }
}

// cumsum over t per (b,s): chunked scan in LDS with conflict-break padding
#define SIDX(t, s) ((t) * 16 + (s) + (((t) >> 5) << 3))
__global__ __launch_bounds__(256) void k_scan(const float* __restrict__ bu, float* __restrict__ hst) {
  __shared__ float buf[8320];
  __shared__ float tot[16][SS];
  int b = blockIdx.x, tid = threadIdx.x;
  for (int i = tid; i < 8192; i += 256) { int t = i >> 4, s = i & 15; buf[SIDX(t, s)] = bu[(size_t)b * 8192 + i]; }
  __syncthreads();
  int s = tid & 15, ck = tid >> 4;
  int base = ck * 32;
  float acc = 0.f;
  for (int i = 0; i < 32; ++i) { acc += buf[SIDX(base + i, s)]; buf[SIDX(base + i, s)] = acc; }
  tot[ck][s] = acc;
  __syncthreads();
  float off = 0.f;
  for (int c2 = 0; c2 < 16; ++c2) if (c2 < ck) off += tot[c2][s];
  for (int i = 0; i < 32; ++i) buf[SIDX(base + i, s)] += off;
  __syncthreads();
  for (int i = tid; i < 8192; i += 256) { int t = i >> 4, s2 = i & 15; hst[(size_t)b * 8192 + i] = buf[SIDX(t, s2)]; }
}

// out-proj: phase A V=(hs@A^T)*gate*mask via K=32 MFMA; phase B sout = V @ out_w^T + b via MFMA
__global__ __launch_bounds__(256) void k_out(const float* __restrict__ hst, const u16* __restrict__ gateB,
    const u16* __restrict__ albB_l, const u16* __restrict__ outwB_l, const float* __restrict__ outb,
    const int* __restrict__ lengths, float* __restrict__ sout) {
  __shared__ alignas(16) u16 hsb[32 * 40];    // stride 40 shorts (80B, 16B-aligned)
  __shared__ alignas(16) u16 vl[32 * 512];    // 32KB V bf16, chunk-XOR swizzled
  int f0 = blockIdx.x * 32, tid = threadIdx.x;
  int len = lengths[f0 >> 9];
  for (int i = tid; i < 512; i += 256) {
    int row = i >> 4, s = i & 15;
    hsb[row * 40 + s] = f2bf(hst[(size_t)(f0 + row) * 16 + s]);
    hsb[row * 40 + 16 + s] = 0;
  }
  __syncthreads();
  int lane = tid & 63, w = tid >> 6, lr = lane & 15, kg = lane >> 4;
  {
    bf16x8 a0 = *(const bf16x8*)&hsb[lr * 40 + kg * 8];
    bf16x8 a1 = *(const bf16x8*)&hsb[(16 + lr) * 40 + kg * 8];
    f32x4 zero = (f32x4){0.f, 0.f, 0.f, 0.f};
#pragma unroll
    for (int fc = 0; fc < 8; ++fc) {
      int h = w * 128 + fc * 16 + lr;
      bf16x8 b = *(const bf16x8*)&albB_l[h * 32 + kg * 8];
      f32x4 va = MFMA16(a0, b, zero, 0, 0, 0);
      f32x4 vb = MFMA16(a1, b, zero, 0, 0, 0);
      int hck = h >> 3, hlo = h & 7;
#pragma unroll
      for (int fr = 0; fr < 2; ++fr) {
        f32x4 vv = fr ? vb : va;
#pragma unroll
        for (int r = 0; r < 4; ++r) {
          int fl = fr * 16 + (lane >> 4) * 4 + r;
          int frame = f0 + fl;
          float g = bf2f(gateB[(size_t)frame * 512 + h]);
          float val = ((frame & 511) < len) ? vv[r] * g : 0.f;
          vl[fl * 512 + ((hck ^ (fl & 7)) << 3) + hlo] = f2bf(val);
        }
      }
    }
  }
  __syncthreads();
  f32x4 acc[2][4];
#pragma unroll
  for (int fr = 0; fr < 2; ++fr)
#pragma unroll
    for (int fc = 0; fc < 4; ++fc) acc[fr][fc] = (f32x4){0.f, 0.f, 0.f, 0.f};
  int db = w * 64;
#pragma unroll
  for (int ks = 0; ks < 16; ++ks) {
    int kc = ks * 4 + kg;
    int r1 = 16 + lr;
    bf16x8 a0 = *(const bf16x8*)&vl[lr * 512 + ((kc ^ (lr & 7)) << 3)];
    bf16x8 a1 = *(const bf16x8*)&vl[r1 * 512 + ((kc ^ (r1 & 7)) << 3)];
#pragma unroll
    for (int fc = 0; fc < 4; ++fc) {
      int d = db + fc * 16 + lr;
      bf16x8 b = *(const bf16x8*)&outwB_l[(size_t)d * 512 + kc * 8];
      acc[0][fc] = MFMA16(a0, b, acc[0][fc], 0, 0, 0);
      acc[1][fc] = MFMA16(a1, b, acc[1][fc], 0, 0, 0);
    }
  }
#pragma unroll
  for (int fr = 0; fr < 2; ++fr)
#pragma unroll
    for (int fc = 0; fc < 4; ++fc) {
      int d = db + fc * 16 + (lane & 15);
      float bias = outb[d];
#pragma unroll
      for (int r = 0; r < 4; ++r) {
        int frame = f0 + fr * 16 + (lane >> 4) * 4 + r;
        sout[(size_t)frame * 256 + d] = acc[fr][fc][r] + bias;
      }
    }
}

// post-LN per frame
__global__ __launch_bounds__(256) void k_postln(const float* __restrict__ seq, const float* __restrict__ w,
    const float* __restrict__ b, float* __restrict__ out) {
  __shared__ float sc[4];
  int f = blockIdx.x, tid = threadIdx.x;
  float v = seq[(size_t)f * DD + tid];
  float mu = red256(v, tid, sc) * (1.f / 256.f);
  float dd = v - mu;
  float var = red256(dd * dd, tid, sc) * (1.f / 256.f);
  float rs = 1.f / sqrtf(var + 1e-5f);
  out[(size_t)f * DD + tid] = fmaf(dd * rs, w[tid], b[tid]);
}

// masked mean pool over t (one block per b)
__global__ __launch_bounds__(256) void k_pool(const float* __restrict__ lnseq, const int* __restrict__ lengths,
    float* __restrict__ pooled) {
  int b = blockIdx.x, d = threadIdx.x;
  int len = lengths[b];
  float acc = 0.f;
  for (int t = 0; t < len; ++t) acc += lnseq[((size_t)b * 512 + t) * DD + d];
  pooled[b * DD + d] = acc / (float)max(len, 1);
}

// wave-per-output MLP: out[16][Nout] = act(in[16][K] @ W^T + b); grid = Nout/4
__global__ __launch_bounds__(256) void k_mlp(const float* __restrict__ in, const float* __restrict__ W,
    const float* __restrict__ bias, float* __restrict__ out, int K, int Nout, int act) {
  __shared__ float lin[16 * 1024];
  int tid = threadIdx.x, lane = tid & 63, w = tid >> 6;
  for (int i = tid; i < 16 * K / 4; i += 256) ((float4*)lin)[i] = ((const float4*)in)[i];
  __syncthreads();
  int o = blockIdx.x * 4 + w;
  const float* wr = W + (size_t)o * K;
  float acc[16];
#pragma unroll
  for (int r = 0; r < 16; ++r) acc[r] = 0.f;
  for (int k = lane; k < K; k += 64) {
    float wv = wr[k];
#pragma unroll
    for (int r = 0; r < 16; ++r) acc[r] = fmaf(lin[r * K + k], wv, acc[r]);
  }
#pragma unroll
  for (int r = 0; r < 16; ++r) {
#pragma unroll
    for (int off = 32; off; off >>= 1) acc[r] += __shfl_xor(acc[r], off);
  }
  if (lane < 16) {
    float v = 0.f;
#pragma unroll
    for (int r = 0; r < 16; ++r) if (lane == r) v = acc[r];   // static-index select
    v += bias[o];
    if (act) v = geluf_(v);
    out[(size_t)lane * Nout + o] = v;
  }
}

// L2 normalize rows of e[16][512]
__global__ __launch_bounds__(256) void k_norm(const float* __restrict__ e, float* __restrict__ out) {
  __shared__ float sc[4];
  int b = blockIdx.x, tid = threadIdx.x;
  float v0 = e[(size_t)b * 512 + tid], v1 = e[(size_t)b * 512 + 256 + tid];
  float ss = red256(v0 * v0 + v1 * v1, tid, sc);
  float nrm = fmaxf(sqrtf(ss), 1e-12f);
  out[(size_t)b * 512 + tid] = v0 / nrm;
  out[(size_t)b * 512 + 256 + tid] = v1 / nrm;
}

// ---------------- launch ----------------

extern "C" void kernel_launch(void* const* d_in, const int* in_sizes, int n_in,
                              void* d_out, int out_size, void* d_ws, size_t ws_size,
                              hipStream_t stream) {
  const float* x         = (const float*)d_in[0];
  const int*   lengths   = (const int*)d_in[1];
  const float* conv1_w   = (const float*)d_in[2];
  const float* bn1_w     = (const float*)d_in[3];
  const float* bn1_b     = (const float*)d_in[4];
  const float* conv2_w   = (const float*)d_in[5];
  const float* bn2_w     = (const float*)d_in[6];
  const float* bn2_b     = (const float*)d_in[7];
  const float* fproj_w   = (const float*)d_in[8];
  const float* fproj_b   = (const float*)d_in[9];
  const float* pre_ln_w  = (const float*)d_in[10];
  const float* pre_ln_b  = (const float*)d_in[11];
  const float* in_w      = (const float*)d_in[12];
  const float* in_b      = (const float*)d_in[13];
  const float* conv_w    = (const float*)d_in[14];
  const float* conv_b    = (const float*)d_in[15];
  const float* A         = (const float*)d_in[16];
  const float* Bm        = (const float*)d_in[17];
  const float* out_w     = (const float*)d_in[18];
  const float* out_b     = (const float*)d_in[19];
  const float* post_ln_w = (const float*)d_in[20];
  const float* post_ln_b = (const float*)d_in[21];
  const float* m1_w      = (const float*)d_in[22];
  const float* m1_b      = (const float*)d_in[23];
  const float* m2_w      = (const float*)d_in[24];
  const float* m2_b      = (const float*)d_in[25];
  const float* m3_w      = (const float*)d_in[26];
  const float* m3_b      = (const float*)d_in[27];
  float* outp = (float*)d_out;

  float* wsf = (float*)d_ws;
  size_t o = 0;
  auto F32 = [&](size_t n) { float* p = wsf + o; o += (n + 63) & ~(size_t)63; return p; };
  float* psum   = F32(1048576);
  float* psq    = F32(1048576);
  float* z2mx   = F32(1048576);
  float* z2mn   = F32(1048576);
  float* mom    = F32(65536);
  float* cc     = F32(512);
  float* s2t2   = F32(256);
  u16*   W2B    = (u16*)F32(8192);      // 16384 bf16
  float* fprojT = F32(32768);
  u16*   inwB   = (u16*)F32(524288);    // 1048576 bf16
  u16*   outwB  = (u16*)F32(262144);    // 524288 bf16
  u16*   albB   = (u16*)F32(32768);     // 65536 bf16
  u16*   BmT    = (u16*)F32(16384);     // 32768 bf16
  float* seqA   = F32(2097152);
  float* seqB   = F32(2097152);
  u16*   gateB  = (u16*)F32(2097152);   // 8192x512 bf16
  u16*   updB   = (u16*)F32(2097152);
  u16*   uB     = (u16*)F32(2097152);
  float* buv    = F32(131072);
  float* hstv   = F32(131072);
  float* pooled = F32(4096);
  float* e1     = F32(16384);
  float* e2     = F32(16384);
  float* e3     = F32(8192);
  if (ws_size < o * sizeof(float)) return;

  const float invM = 1.f / (float)(NFRM * NPT);

  k_prep<<<6720, 256, 0, stream>>>(conv2_w, fproj_w, in_w, out_w, A, Bm,
                                   W2B, fprojT, inwB, outwB, albB, BmT);
  k_mom<<<2048, 256, 0, stream>>>(x, mom);
  k_stats<<<1, 256, 0, stream>>>(mom, conv1_w, bn1_w, bn1_b, cc);
  k2_main<<<NFRM / 4, 256, 0, stream>>>(x, (const float4*)cc, W2B, z2mx, z2mn, psum, psq);
  k_red<<<CH, 256, 0, stream>>>(psum, psq, bn2_w, bn2_b, s2t2, invM, 1e-5f);
  k4_feat<<<NFRM / 8, 256, 0, stream>>>(z2mx, z2mn, s2t2, fprojT, fproj_b, pre_ln_w, pre_ln_b, seqA);

  for (int l = 0; l < NL; ++l) {
    const float* sin = (l & 1) ? seqB : seqA;
    float* sout      = (l & 1) ? seqA : seqB;
    k_in<<<NFRM / 32, 512, 0, stream>>>(sin, inwB + (size_t)l * 262144, in_b + l * 1024, gateB, updB);
    k_conv<<<NFRM * HH / 256, 256, 0, stream>>>(updB, conv_w + l * 2048, conv_b + l * 512, uB);
    k_bu<<<NFRM / 64, 256, 0, stream>>>(uB, BmT + (size_t)l * 8192, lengths, buv);
    k_scan<<<16, 256, 0, stream>>>(buv, hstv);
    k_out<<<NFRM / 32, 256, 0, stream>>>(hstv, gateB, albB + (size_t)l * 16384,
                                         outwB + (size_t)l * 131072, out_b + l * 256, lengths, sout);
  }
  k_postln<<<NFRM, 256, 0, stream>>>(seqA, post_ln_w, post_ln_b, seqB);
  k_pool<<<16, 256, 0, stream>>>(seqB, lengths, pooled);
  k_mlp<<<256, 256, 0, stream>>>(pooled, m1_w, m1_b, e1, 256, 1024, 1);
  k_mlp<<<256, 256, 0, stream>>>(e1, m2_w, m2_b, e2, 1024, 1024, 1);
  k_mlp<<<128, 256, 0, stream>>>(e2, m3_w, m3_b, e3, 1024, 512, 0);
  k_norm<<<16, 256, 0, stream>>>(e3, outp);
}

// Round 5
// 516.723 us; speedup vs baseline: 3.9906x; 1.3691x over previous
//
#include <hip/hip_runtime.h>
#include <hip/hip_bf16.h>
#include <math.h>

#define NFRM 8192   // B*T
#define NPT  128    // N points
#define CH   128    // HID
#define DD   256    // D
#define HH   512    // H
#define SS   16     // S
#define NL   4

typedef __attribute__((ext_vector_type(8))) short bf16x8;
typedef __attribute__((ext_vector_type(4))) float f32x4;
typedef unsigned short u16;

#define MFMA16 __builtin_amdgcn_mfma_f32_16x16x32_bf16

// ---------------- helpers ----------------

__device__ __forceinline__ float red256(float v, int tid, volatile float* sc) {
#pragma unroll
  for (int off = 32; off; off >>= 1) v += __shfl_down(v, off);
  __syncthreads();
  if ((tid & 63) == 0) sc[tid >> 6] = v;
  __syncthreads();
  return sc[0] + sc[1] + sc[2] + sc[3];
}

__device__ __forceinline__ float sigmoidf_(float x) { return 1.f / (1.f + __expf(-x)); }
__device__ __forceinline__ float geluf_(float x) { return 0.5f * x * (1.f + erff(x * 0.70710678118654752f)); }

// f32 -> bf16 bits (compiler emits v_cvt_pk_bf16_f32 for pairs)
__device__ __forceinline__ u16 f2bf(float f) {
  __hip_bfloat16 h = __float2bfloat16(f);
  return *(u16*)&h;
}
__device__ __forceinline__ float bf2f(u16 u) {
  union { unsigned int i; float f; } v; v.i = ((unsigned int)u) << 16; return v.f;
}

// ---------------- kernels ----------------

// pack weights: W2B bf16 swizzled; fprojT f32; inwB/outwB flat bf16 cast; albB zero-padded; BmT transposed
__global__ __launch_bounds__(256) void k_prep(const float* __restrict__ conv2_w,
    const float* __restrict__ fproj_w, const float* __restrict__ in_w, const float* __restrict__ out_w,
    const float* __restrict__ A, const float* __restrict__ Bm,
    u16* __restrict__ W2B, float* __restrict__ fprojT, u16* __restrict__ inwB,
    u16* __restrict__ outwB, u16* __restrict__ albB, u16* __restrict__ BmT) {
  int idx = blockIdx.x * 256 + threadIdx.x;
  if (idx < 16384) {
    int c = idx >> 7, k = idx & 127;
    int dst = c * 128 + ((((k >> 3) ^ (c & 7)) << 3) | (k & 7));
    W2B[dst] = f2bf(conv2_w[idx]);
    return;
  }
  idx -= 16384;
  if (idx < 32768) { int c = idx >> 8, d = idx & 255; fprojT[idx] = fproj_w[d * 128 + c]; return; }
  idx -= 32768;
  if (idx < 1048576) { inwB[idx] = f2bf(in_w[idx]); return; }
  idx -= 1048576;
  if (idx < 524288) { outwB[idx] = f2bf(out_w[idx]); return; }
  idx -= 524288;
  if (idx < 65536) {
    int l = idx >> 14, rem = idx & 16383, h = rem >> 5, kk = rem & 31;
    albB[idx] = (kk < 16) ? f2bf(A[(size_t)l * 8192 + h * 16 + kk]) : (u16)0;
    return;
  }
  idx -= 65536;
  if (idx < 32768) {
    int l = idx >> 13, rem = idx & 8191, s = rem >> 9, h = rem & 511;
    BmT[idx] = f2bf(Bm[(size_t)l * 8192 + h * 16 + s]);
  }
}

// per-frame moments: mom[f][0..5]=Cij/(sdi*sdj); msd[f]= (mu0,mu1,mu2,0, rsd0,rsd1,rsd2,0)
__global__ __launch_bounds__(256) void k_mom(const float* __restrict__ x, float* __restrict__ mom,
                                             float* __restrict__ msd) {
  int tid = threadIdx.x, lane = tid & 63, w = tid >> 6;
  int f = blockIdx.x * 4 + w;
  const float* xf = x + (size_t)f * 384 + lane * 6;
  float a0 = xf[0], a1 = xf[1], a2 = xf[2], b0 = xf[3], b1 = xf[4], b2 = xf[5];
  float s0 = a0 + b0, s1 = a1 + b1, s2 = a2 + b2;
  float p00 = a0*a0 + b0*b0, p01 = a0*a1 + b0*b1, p02 = a0*a2 + b0*b2;
  float p11 = a1*a1 + b1*b1, p12 = a1*a2 + b1*b2, p22 = a2*a2 + b2*b2;
#pragma unroll
  for (int off = 32; off; off >>= 1) {
    s0 += __shfl_down(s0, off); s1 += __shfl_down(s1, off); s2 += __shfl_down(s2, off);
    p00 += __shfl_down(p00, off); p01 += __shfl_down(p01, off); p02 += __shfl_down(p02, off);
    p11 += __shfl_down(p11, off); p12 += __shfl_down(p12, off); p22 += __shfl_down(p22, off);
  }
  if (lane == 0) {
    float mu0 = s0 * (1.f/128.f), mu1 = s1 * (1.f/128.f), mu2 = s2 * (1.f/128.f);
    float C00 = p00 - 128.f*mu0*mu0, C01 = p01 - 128.f*mu0*mu1, C02 = p02 - 128.f*mu0*mu2;
    float C11 = p11 - 128.f*mu1*mu1, C12 = p12 - 128.f*mu1*mu2, C22 = p22 - 128.f*mu2*mu2;
    float sd0 = sqrtf(C00 * (1.f/127.f)) + 1e-10f;
    float sd1 = sqrtf(C11 * (1.f/127.f)) + 1e-10f;
    float sd2 = sqrtf(C22 * (1.f/127.f)) + 1e-10f;
    float* m = mom + (size_t)f * 8;
    m[0] = C00/(sd0*sd0); m[1] = C01/(sd0*sd1); m[2] = C02/(sd0*sd2);
    m[3] = C11/(sd1*sd1); m[4] = C12/(sd1*sd2); m[5] = C22/(sd2*sd2);
    float* d = msd + (size_t)f * 8;
    d[0] = mu0; d[1] = mu1; d[2] = mu2; d[3] = 0.f;
    d[4] = 1.f/sd0; d[5] = 1.f/sd1; d[6] = 1.f/sd2; d[7] = 0.f;
  }
}

// stage 1: 64 blocks x 128 frames -> pstat[64][8]
__global__ __launch_bounds__(256) void k_stats1(const float* __restrict__ mom, float* __restrict__ pstat) {
  __shared__ float part[32][8];
  int tid = threadIdx.x, j = tid & 7, g = tid >> 3;
  int f0 = blockIdx.x * 128;
  float sm = 0.f;
  if (j < 6) {
#pragma unroll
    for (int k = 0; k < 4; ++k) sm += mom[(size_t)(f0 + g + k * 32) * 8 + j];
  }
  part[g][j] = sm;
  __syncthreads();
  if (tid < 8) {
    float tot = 0.f;
    for (int g2 = 0; g2 < 32; ++g2) tot += part[g2][tid];
    pstat[blockIdx.x * 8 + tid] = tot;
  }
}

// stage 2: final bn1 folded channel constants cc[c] = (s*w0, s*w1, s*w2, t)
__global__ __launch_bounds__(256) void k_stats2(const float* __restrict__ pstat, const float* __restrict__ w1,
    const float* __restrict__ bw, const float* __restrict__ bb, float* __restrict__ cc) {
  __shared__ float part[32][8];
  __shared__ float Mt[8];
  int tid = threadIdx.x, j = tid & 7, g = tid >> 3;
  if (tid < 256) part[g][j] = pstat[g * 8 + j] + pstat[(g + 32) * 8 + j];
  __syncthreads();
  if (tid < 8) { float tot = 0.f; for (int g2 = 0; g2 < 32; ++g2) tot += part[g2][tid]; Mt[tid] = tot; }
  __syncthreads();
  if (tid < 128) {
    float w0 = w1[tid*3], wa = w1[tid*3+1], wb = w1[tid*3+2];
    float var = (w0*w0*Mt[0] + wa*wa*Mt[3] + wb*wb*Mt[5]
               + 2.f*(w0*wa*Mt[1] + w0*wb*Mt[2] + wa*wb*Mt[4])) * (1.f/1048576.f);
    float s = bw[tid] / sqrtf(var + 1e-5f);
    ((float4*)cc)[tid] = make_float4(s*w0, s*wa, s*wb, bb[tid]);
  }
}

// main fused kernel: 4 frames/block; h1 fragments built in regs from precomputed mu/rsd; MFMA GEMM
__global__ __launch_bounds__(256) void k2_main(const float* __restrict__ x, const float4* __restrict__ cc,
    const float4* __restrict__ msd4, const u16* __restrict__ W2B,
    float* __restrict__ z2mx, float* __restrict__ z2mn,
    float* __restrict__ psum, float* __restrict__ psq) {
  __shared__ alignas(16) u16 w2s[16384];     // 32KB, pre-swizzled
  __shared__ float4 ccs[128];
  __shared__ float smx[4][CH], smn[4][CH], ssm[4][CH], ssq[4][CH];
  int tid = threadIdx.x;
  for (int i = tid; i < 2048; i += 256) ((float4*)w2s)[i] = ((const float4*)W2B)[i];
  if (tid < 128) ccs[tid] = cc[tid];
  int lane = tid & 63, w = tid >> 6;
  int lr = lane & 15, kg = lane >> 4;
  int row0 = w * 32 + lr, row1 = row0 + 16;
  for (int fi = 0; fi < 4; ++fi) {
    int f = blockIdx.x * 4 + fi;
    __syncthreads();                         // w2s ready (fi=0) / smx reuse guard
    float4 mu4 = msd4[f * 2], rs4 = msd4[f * 2 + 1];
    const float* xr0 = x + (size_t)f * 384 + row0 * 3;
    const float* xr1 = x + (size_t)f * 384 + row1 * 3;
    float xa0 = (xr0[0] - mu4.x) * rs4.x, xa1 = (xr0[1] - mu4.y) * rs4.y, xa2 = (xr0[2] - mu4.z) * rs4.z;
    float xb0 = (xr1[0] - mu4.x) * rs4.x, xb1 = (xr1[1] - mu4.y) * rs4.y, xb2 = (xr1[2] - mu4.z) * rs4.z;
    f32x4 acc[2][8];
#pragma unroll
    for (int fr = 0; fr < 2; ++fr)
#pragma unroll
      for (int fc = 0; fc < 8; ++fc) acc[fr][fc] = (f32x4){0.f, 0.f, 0.f, 0.f};
#pragma unroll
    for (int ks = 0; ks < 4; ++ks) {
      int kc = ks * 4 + kg, c0 = kc * 8;
      bf16x8 a0, a1;
#pragma unroll
      for (int q = 0; q < 8; ++q) {
        float4 c4 = ccs[c0 + q];
        float h0 = fmaxf(0.f, fmaf(xa0, c4.x, fmaf(xa1, c4.y, fmaf(xa2, c4.z, c4.w))));
        float h1 = fmaxf(0.f, fmaf(xb0, c4.x, fmaf(xb1, c4.y, fmaf(xb2, c4.z, c4.w))));
        a0[q] = (short)f2bf(h0); a1[q] = (short)f2bf(h1);
      }
#pragma unroll
      for (int fc = 0; fc < 8; ++fc) {
        int col = fc * 16 + lr;
        bf16x8 b = *(const bf16x8*)&w2s[col * 128 + ((kc ^ (col & 7)) << 3)];
        acc[0][fc] = MFMA16(a0, b, acc[0][fc], 0, 0, 0);
        acc[1][fc] = MFMA16(a1, b, acc[1][fc], 0, 0, 0);
      }
    }
    // per-channel stats
#pragma unroll
    for (int fc = 0; fc < 8; ++fc) {
      float mx = -3e38f, mn = 3e38f, sm = 0.f, sq = 0.f;
#pragma unroll
      for (int fr = 0; fr < 2; ++fr)
#pragma unroll
        for (int r = 0; r < 4; ++r) {
          float v = acc[fr][fc][r];
          mx = fmaxf(mx, v); mn = fminf(mn, v); sm += v; sq = fmaf(v, v, sq);
        }
#pragma unroll
      for (int off = 16; off <= 32; off <<= 1) {
        mx = fmaxf(mx, __shfl_xor(mx, off));
        mn = fminf(mn, __shfl_xor(mn, off));
        sm += __shfl_xor(sm, off);
        sq += __shfl_xor(sq, off);
      }
      if (lane < 16) {
        int col = fc * 16 + lr;
        smx[w][col] = mx; smn[w][col] = mn; ssm[w][col] = sm; ssq[w][col] = sq;
      }
    }
    __syncthreads();
    if (tid < CH) {
      float mx = smx[0][tid], mn = smn[0][tid], sm = ssm[0][tid], sq = ssq[0][tid];
#pragma unroll
      for (int w2 = 1; w2 < 4; ++w2) {
        mx = fmaxf(mx, smx[w2][tid]); mn = fminf(mn, smn[w2][tid]);
        sm += ssm[w2][tid]; sq += ssq[w2][tid];
      }
      z2mx[(size_t)f * CH + tid] = mx;
      z2mn[(size_t)f * CH + tid] = mn;
      psum[(size_t)f * CH + tid] = sm;
      psq[(size_t)f * CH + tid]  = sq;
    }
  }
}

// bn2 reduce stage 1: 64 blocks x 128 frames, coalesced
__global__ __launch_bounds__(256) void k_red1(const float* __restrict__ psum, const float* __restrict__ psq,
    float* __restrict__ prs, float* __restrict__ prq) {
  __shared__ float s0[2][128], s1[2][128];
  int tid = threadIdx.x, c = tid & 127, half = tid >> 7;
  int f0 = blockIdx.x * 128;
  float sm = 0.f, sq = 0.f;
  for (int fl = half; fl < 128; fl += 2) {
    size_t idx = (size_t)(f0 + fl) * 128 + c;
    sm += psum[idx]; sq += psq[idx];
  }
  s0[half][c] = sm; s1[half][c] = sq;
  __syncthreads();
  if (tid < 128) {
    prs[blockIdx.x * 128 + tid] = s0[0][tid] + s0[1][tid];
    prq[blockIdx.x * 128 + tid] = s1[0][tid] + s1[1][tid];
  }
}

// bn2 reduce stage 2 -> scale/shift
__global__ __launch_bounds__(256) void k_red2(const float* __restrict__ prs, const float* __restrict__ prq,
    const float* __restrict__ w, const float* __restrict__ b, float* __restrict__ st,
    float invM, float eps) {
  __shared__ float s0[2][128], s1[2][128];
  int tid = threadIdx.x, c = tid & 127, half = tid >> 7;
  float sm = 0.f, sq = 0.f;
  for (int g = half; g < 64; g += 2) { sm += prs[g * 128 + c]; sq += prq[g * 128 + c]; }
  s0[half][c] = sm; s1[half][c] = sq;
  __syncthreads();
  if (tid < 128) {
    float tsm = s0[0][tid] + s0[1][tid], tsq = s1[0][tid] + s1[1][tid];
    float mean = tsm * invM;
    float var = tsq * invM - mean * mean;
    float s = w[tid] / sqrtf(var + eps);
    st[tid] = s;
    st[CH + tid] = b[tid] - mean * s;
  }
}

// feat = relu(bn2(z2ext)) @ fprojT + b ; pre-LN -> seq  (8 frames/block, wave-per-row LN)
__global__ __launch_bounds__(256) void k4_feat(const float* __restrict__ z2mx, const float* __restrict__ z2mn,
    const float* __restrict__ s2t2, const float* __restrict__ fprojT, const float* __restrict__ fpb,
    const float* __restrict__ plw, const float* __restrict__ plb, float* __restrict__ seq) {
  __shared__ float h2[8][CH];
  int f0 = blockIdx.x * 8, tid = threadIdx.x;
  for (int i = tid; i < 8 * CH; i += 256) {
    int r = i >> 7, c = i & 127;
    float s = s2t2[c], t = s2t2[CH + c];
    float z = (s >= 0.f) ? z2mx[(size_t)(f0 + r) * CH + c] : z2mn[(size_t)(f0 + r) * CH + c];
    h2[r][c] = fmaxf(0.f, fmaf(s, z, t));
  }
  __syncthreads();
  int lane = tid & 63, w = tid >> 6;
  const float4* fp4 = (const float4*)fprojT;   // [c][64] float4
  float4 fpb4 = ((const float4*)fpb)[lane];
  float4 plw4 = ((const float4*)plw)[lane];
  float4 plb4 = ((const float4*)plb)[lane];
  int rA = w, rB = w + 4;
  float4 accA = fpb4, accB = fpb4;
  for (int c = 0; c < CH; ++c) {
    float4 wv = fp4[c * 64 + lane];
    float ha = h2[rA][c], hb = h2[rB][c];
    accA.x = fmaf(ha, wv.x, accA.x); accA.y = fmaf(ha, wv.y, accA.y);
    accA.z = fmaf(ha, wv.z, accA.z); accA.w = fmaf(ha, wv.w, accA.w);
    accB.x = fmaf(hb, wv.x, accB.x); accB.y = fmaf(hb, wv.y, accB.y);
    accB.z = fmaf(hb, wv.z, accB.z); accB.w = fmaf(hb, wv.w, accB.w);
  }
#pragma unroll
  for (int rr = 0; rr < 2; ++rr) {
    float4 a = rr ? accB : accA;
    int r = rr ? rB : rA;
    float s = a.x + a.y + a.z + a.w;
#pragma unroll
    for (int off = 32; off; off >>= 1) s += __shfl_xor(s, off);
    float mu = s * (1.f / 256.f);
    float4 dd = make_float4(a.x - mu, a.y - mu, a.z - mu, a.w - mu);
    float q = dd.x*dd.x + dd.y*dd.y + dd.z*dd.z + dd.w*dd.w;
#pragma unroll
    for (int off = 32; off; off >>= 1) q += __shfl_xor(q, off);
    float rs = 1.f / sqrtf(q * (1.f / 256.f) + 1e-5f);
    float4 o;
    o.x = fmaf(dd.x * rs, plw4.x, plb4.x); o.y = fmaf(dd.y * rs, plw4.y, plb4.y);
    o.z = fmaf(dd.z * rs, plw4.z, plb4.z); o.w = fmaf(dd.w * rs, plw4.w, plb4.w);
    ((float4*)(seq + (size_t)(f0 + r) * DD))[lane] = o;
  }
}

// in-proj via MFMA: 32 frames x 1024 cols, 8 waves; gate/upd out bf16
__global__ __launch_bounds__(512) void k_in(const float* __restrict__ seq, const u16* __restrict__ inwB_l,
    const float* __restrict__ inb, u16* __restrict__ gate, u16* __restrict__ upd) {
  __shared__ alignas(16) u16 as[32 * 256];   // 16KB bf16, chunk-XOR swizzled
  int f0 = blockIdx.x * 32, tid = threadIdx.x;
  for (int c = tid; c < 1024; c += 512) {
    int row = c >> 5, cc = c & 31;
    const float* src = seq + (size_t)(f0 + row) * 256 + cc * 8;
    float4 u0 = *(const float4*)src, u1 = *(const float4*)(src + 4);
    bf16x8 v;
    v[0] = (short)f2bf(u0.x); v[1] = (short)f2bf(u0.y); v[2] = (short)f2bf(u0.z); v[3] = (short)f2bf(u0.w);
    v[4] = (short)f2bf(u1.x); v[5] = (short)f2bf(u1.y); v[6] = (short)f2bf(u1.z); v[7] = (short)f2bf(u1.w);
    *(bf16x8*)&as[row * 256 + ((cc ^ (row & 7)) << 3)] = v;
  }
  __syncthreads();
  int lane = tid & 63, w = tid >> 6;
  int lr = lane & 15, kg = lane >> 4;
  int colb = w * 128;
  f32x4 acc[2][8];
#pragma unroll
  for (int fr = 0; fr < 2; ++fr)
#pragma unroll
    for (int fc = 0; fc < 8; ++fc) acc[fr][fc] = (f32x4){0.f, 0.f, 0.f, 0.f};
#pragma unroll
  for (int ks = 0; ks < 8; ++ks) {
    int kc = ks * 4 + kg;
    int r1 = 16 + lr;
    bf16x8 a0 = *(const bf16x8*)&as[lr * 256 + ((kc ^ (lr & 7)) << 3)];
    bf16x8 a1 = *(const bf16x8*)&as[r1 * 256 + ((kc ^ (r1 & 7)) << 3)];
#pragma unroll
    for (int fc = 0; fc < 8; ++fc) {
      int col = colb + fc * 16 + lr;
      bf16x8 b = *(const bf16x8*)&inwB_l[(size_t)col * 256 + kc * 8];
      acc[0][fc] = MFMA16(a0, b, acc[0][fc], 0, 0, 0);
      acc[1][fc] = MFMA16(a1, b, acc[1][fc], 0, 0, 0);
    }
  }
  bool isGate = (w < 4);
  u16* dst = isGate ? gate : upd;
  int cbOff = isGate ? 0 : 512;
#pragma unroll
  for (int fr = 0; fr < 2; ++fr)
#pragma unroll
    for (int fc = 0; fc < 8; ++fc) {
      int cg = colb + fc * 16 + (lane & 15);
      float bias = inb[cg];
      int colOut = cg - cbOff;
#pragma unroll
      for (int r = 0; r < 4; ++r) {
        int frame = f0 + fr * 16 + (lane >> 4) * 4 + r;
        float v = acc[fr][fc][r] + bias;
        float sg = sigmoidf_(v);
        v = isGate ? sg : v * sg;
        dst[(size_t)frame * 512 + colOut] = f2bf(v);
      }
    }
}

// depthwise conv along T, kernel 4, pad(2,2) crop :T  (bf16 in/out)
__global__ __launch_bounds__(256) void k_conv(const u16* __restrict__ updB, const float* __restrict__ cw,
    const float* __restrict__ cb, u16* __restrict__ uB) {
  int idx = blockIdx.x * 256 + threadIdx.x;    // NFRM*HH
  int h = idx & 511, f = idx >> 9;
  int t = f & 511;
  const u16* base = updB + (size_t)(f - t) * 512 + h;
  float4 cw4 = ((const float4*)cw)[h];
  float v = cb[h];
  if (t >= 2) v = fmaf(cw4.x, bf2f(base[(t - 2) * 512]), v);
  if (t >= 1) v = fmaf(cw4.y, bf2f(base[(t - 1) * 512]), v);
  v = fmaf(cw4.z, bf2f(base[t * 512]), v);
  if (t < 511) v = fmaf(cw4.w, bf2f(base[(t + 1) * 512]), v);
  uB[idx] = f2bf(v);
}

// Bu = u @ Bm (masked) via MFMA; stores [b][s][t] layout for the scan
__global__ __launch_bounds__(256) void k_bu(const u16* __restrict__ uB, const u16* __restrict__ BmT_l,
    const int* __restrict__ lengths, float* __restrict__ bu) {
  int tid = threadIdx.x, lane = tid & 63, w = tid >> 6;
  int f0 = blockIdx.x * 64 + w * 16;
  int lr = lane & 15, kg = lane >> 4;
  f32x4 acc = (f32x4){0.f, 0.f, 0.f, 0.f};
#pragma unroll
  for (int ks = 0; ks < 16; ++ks) {
    int kc = ks * 4 + kg;
    bf16x8 a = *(const bf16x8*)&uB[(size_t)(f0 + lr) * 512 + kc * 8];
    bf16x8 b = *(const bf16x8*)&BmT_l[lr * 512 + kc * 8];
    acc = MFMA16(a, b, acc, 0, 0, 0);
  }
  int s = lane & 15;
#pragma unroll
  for (int r = 0; r < 4; ++r) {
    int frame = f0 + (lane >> 4) * 4 + r;
    int t = frame & 511, bi = frame >> 9;
    bu[((size_t)bi * 16 + s) * 512 + t] = (t < lengths[bi]) ? acc[r] : 0.f;
  }
}

// cumsum over t per (b,s): one wave per scan, [b][s][t] layout
__global__ __launch_bounds__(256) void k_scan(const float* __restrict__ bu, float* __restrict__ hst) {
  int tid = threadIdx.x, lane = tid & 63, w = tid >> 6;
  int gw = blockIdx.x * 4 + w;
  const float* src = bu + (size_t)gw * 512 + lane * 8;
  float4 v0 = *(const float4*)src, v1 = *(const float4*)(src + 4);
  float p0 = v0.x, p1 = p0 + v0.y, p2 = p1 + v0.z, p3 = p2 + v0.w;
  float p4 = p3 + v1.x, p5 = p4 + v1.y, p6 = p5 + v1.z, p7 = p6 + v1.w;
  float tot = p7;
#pragma unroll
  for (int off = 1; off < 64; off <<= 1) {
    float n = __shfl_up(tot, off);
    if (lane >= off) tot += n;
  }
  float excl = tot - p7;
  float4 o0 = make_float4(p0 + excl, p1 + excl, p2 + excl, p3 + excl);
  float4 o1 = make_float4(p4 + excl, p5 + excl, p6 + excl, p7 + excl);
  float* dst = hst + (size_t)gw * 512 + lane * 8;
  *(float4*)dst = o0; *(float4*)(dst + 4) = o1;
}

// out-proj: phase A V=(hs@A^T)*gate*mask via K=32 MFMA; phase B sout = V @ out_w^T + b via MFMA
__global__ __launch_bounds__(256) void k_out(const float* __restrict__ hst, const u16* __restrict__ gateB,
    const u16* __restrict__ albB_l, const u16* __restrict__ outwB_l, const float* __restrict__ outb,
    const int* __restrict__ lengths, float* __restrict__ sout) {
  __shared__ alignas(16) u16 hsb[32 * 40];    // stride 40 shorts (80B, 16B-aligned)
  __shared__ alignas(16) u16 vl[32 * 512];    // 32KB V bf16, chunk-XOR swizzled
  int f0 = blockIdx.x * 32, tid = threadIdx.x;
  int bb = f0 >> 9, tbase = f0 & 511;
  int len = lengths[bb];
  for (int i = tid; i < 512; i += 256) {
    int row = i >> 4, s = i & 15;
    hsb[row * 40 + s] = f2bf(hst[((size_t)bb * 16 + s) * 512 + tbase + row]);
    hsb[row * 40 + 16 + s] = 0;
  }
  __syncthreads();
  int lane = tid & 63, w = tid >> 6, lr = lane & 15, kg = lane >> 4;
  {
    bf16x8 a0 = *(const bf16x8*)&hsb[lr * 40 + kg * 8];
    bf16x8 a1 = *(const bf16x8*)&hsb[(16 + lr) * 40 + kg * 8];
    f32x4 zero = (f32x4){0.f, 0.f, 0.f, 0.f};
#pragma unroll
    for (int fc = 0; fc < 8; ++fc) {
      int h = w * 128 + fc * 16 + lr;
      bf16x8 b = *(const bf16x8*)&albB_l[h * 32 + kg * 8];
      f32x4 va = MFMA16(a0, b, zero, 0, 0, 0);
      f32x4 vb = MFMA16(a1, b, zero, 0, 0, 0);
      int hck = h >> 3, hlo = h & 7;
#pragma unroll
      for (int fr = 0; fr < 2; ++fr) {
        f32x4 vv = fr ? vb : va;
#pragma unroll
        for (int r = 0; r < 4; ++r) {
          int fl = fr * 16 + (lane >> 4) * 4 + r;
          int frame = f0 + fl;
          float g = bf2f(gateB[(size_t)frame * 512 + h]);
          float val = ((frame & 511) < len) ? vv[r] * g : 0.f;
          vl[fl * 512 + ((hck ^ (fl & 7)) << 3) + hlo] = f2bf(val);
        }
      }
    }
  }
  __syncthreads();
  f32x4 acc[2][4];
#pragma unroll
  for (int fr = 0; fr < 2; ++fr)
#pragma unroll
    for (int fc = 0; fc < 4; ++fc) acc[fr][fc] = (f32x4){0.f, 0.f, 0.f, 0.f};
  int db = w * 64;
#pragma unroll
  for (int ks = 0; ks < 16; ++ks) {
    int kc = ks * 4 + kg;
    int r1 = 16 + lr;
    bf16x8 a0 = *(const bf16x8*)&vl[lr * 512 + ((kc ^ (lr & 7)) << 3)];
    bf16x8 a1 = *(const bf16x8*)&vl[r1 * 512 + ((kc ^ (r1 & 7)) << 3)];
#pragma unroll
    for (int fc = 0; fc < 4; ++fc) {
      int d = db + fc * 16 + lr;
      bf16x8 b = *(const bf16x8*)&outwB_l[(size_t)d * 512 + kc * 8];
      acc[0][fc] = MFMA16(a0, b, acc[0][fc], 0, 0, 0);
      acc[1][fc] = MFMA16(a1, b, acc[1][fc], 0, 0, 0);
    }
  }
#pragma unroll
  for (int fr = 0; fr < 2; ++fr)
#pragma unroll
    for (int fc = 0; fc < 4; ++fc) {
      int d = db + fc * 16 + (lane & 15);
      float bias = outb[d];
#pragma unroll
      for (int r = 0; r < 4; ++r) {
        int frame = f0 + fr * 16 + (lane >> 4) * 4 + r;
        sout[(size_t)frame * 256 + d] = acc[fr][fc][r] + bias;
      }
    }
}

// post-LN: wave per frame
__global__ __launch_bounds__(256) void k_postln(const float* __restrict__ seq, const float* __restrict__ w,
    const float* __restrict__ b, float* __restrict__ out) {
  int tid = threadIdx.x, lane = tid & 63;
  int f = blockIdx.x * 4 + (tid >> 6);
  float4 v = ((const float4*)(seq + (size_t)f * DD))[lane];
  float s = v.x + v.y + v.z + v.w;
#pragma unroll
  for (int off = 32; off; off >>= 1) s += __shfl_xor(s, off);
  float mu = s * (1.f / 256.f);
  float4 dd = make_float4(v.x - mu, v.y - mu, v.z - mu, v.w - mu);
  float q = dd.x*dd.x + dd.y*dd.y + dd.z*dd.z + dd.w*dd.w;
#pragma unroll
  for (int off = 32; off; off >>= 1) q += __shfl_xor(q, off);
  float rs = 1.f / sqrtf(q * (1.f / 256.f) + 1e-5f);
  float4 w4 = ((const float4*)w)[lane], b4 = ((const float4*)b)[lane];
  float4 o;
  o.x = fmaf(dd.x * rs, w4.x, b4.x); o.y = fmaf(dd.y * rs, w4.y, b4.y);
  o.z = fmaf(dd.z * rs, w4.z, b4.z); o.w = fmaf(dd.w * rs, w4.w, b4.w);
  ((float4*)(out + (size_t)f * DD))[lane] = o;
}

// masked mean pool over t (one block per b), float4 + 4-way t split
__global__ __launch_bounds__(256) void k_pool(const float* __restrict__ lnseq, const int* __restrict__ lengths,
    float* __restrict__ pooled) {
  __shared__ float4 part[4][64];
  int b = blockIdx.x, tid = threadIdx.x;
  int dq = tid & 63, q = tid >> 6;
  int len = lengths[b];
  float4 acc = make_float4(0.f, 0.f, 0.f, 0.f);
  for (int t = q; t < len; t += 4) {
    float4 v = ((const float4*)(lnseq + ((size_t)b * 512 + t) * DD))[dq];
    acc.x += v.x; acc.y += v.y; acc.z += v.z; acc.w += v.w;
  }
  part[q][dq] = acc;
  __syncthreads();
  if (tid < 64) {
    float4 a0 = part[0][tid], a1 = part[1][tid], a2 = part[2][tid], a3 = part[3][tid];
    float inv = 1.f / (float)max(len, 1);
    float4 o;
    o.x = (a0.x + a1.x + a2.x + a3.x) * inv;
    o.y = (a0.y + a1.y + a2.y + a3.y) * inv;
    o.z = (a0.z + a1.z + a2.z + a3.z) * inv;
    o.w = (a0.w + a1.w + a2.w + a3.w) * inv;
    ((float4*)(pooled + (size_t)b * DD))[tid] = o;
  }
}

// wave-per-output MLP: out[16][Nout] = act(in[16][K] @ W^T + b); grid = Nout/4
__global__ __launch_bounds__(256) void k_mlp(const float* __restrict__ in, const float* __restrict__ W,
    const float* __restrict__ bias, float* __restrict__ out, int K, int Nout, int act) {
  __shared__ float lin[16 * 1024];
  int tid = threadIdx.x, lane = tid & 63, w = tid >> 6;
  for (int i = tid; i < 16 * K / 4; i += 256) ((float4*)lin)[i] = ((const float4*)in)[i];
  __syncthreads();
  int o = blockIdx.x * 4 + w;
  const float* wr = W + (size_t)o * K;
  float acc[16];
#pragma unroll
  for (int r = 0; r < 16; ++r) acc[r] = 0.f;
  for (int k = lane; k < K; k += 64) {
    float wv = wr[k];
#pragma unroll
    for (int r = 0; r < 16; ++r) acc[r] = fmaf(lin[r * K + k], wv, acc[r]);
  }
#pragma unroll
  for (int r = 0; r < 16; ++r) {
#pragma unroll
    for (int off = 32; off; off >>= 1) acc[r] += __shfl_xor(acc[r], off);
  }
  if (lane < 16) {
    float v = 0.f;
#pragma unroll
    for (int r = 0; r < 16; ++r) if (lane == r) v = acc[r];   // static-index select
    v += bias[o];
    if (act) v = geluf_(v);
    out[(size_t)lane * Nout + o] = v;
  }
}

// L2 normalize rows of e[16][512]
__global__ __launch_bounds__(256) void k_norm(const float* __restrict__ e, float* __restrict__ out) {
  __shared__ float sc[4];
  int b = blockIdx.x, tid = threadIdx.x;
  float v0 = e[(size_t)b * 512 + tid], v1 = e[(size_t)b * 512 + 256 + tid];
  float ss = red256(v0 * v0 + v1 * v1, tid, sc);
  float nrm = fmaxf(sqrtf(ss), 1e-12f);
  out[(size_t)b * 512 + tid] = v0 / nrm;
  out[(size_t)b * 512 + 256 + tid] = v1 / nrm;
}

// ---------------- launch ----------------

extern "C" void kernel_launch(void* const* d_in, const int* in_sizes, int n_in,
                              void* d_out, int out_size, void* d_ws, size_t ws_size,
                              hipStream_t stream) {
  const float* x         = (const float*)d_in[0];
  const int*   lengths   = (const int*)d_in[1];
  const float* conv1_w   = (const float*)d_in[2];
  const float* bn1_w     = (const float*)d_in[3];
  const float* bn1_b     = (const float*)d_in[4];
  const float* conv2_w   = (const float*)d_in[5];
  const float* bn2_w     = (const float*)d_in[6];
  const float* bn2_b     = (const float*)d_in[7];
  const float* fproj_w   = (const float*)d_in[8];
  const float* fproj_b   = (const float*)d_in[9];
  const float* pre_ln_w  = (const float*)d_in[10];
  const float* pre_ln_b  = (const float*)d_in[11];
  const float* in_w      = (const float*)d_in[12];
  const float* in_b      = (const float*)d_in[13];
  const float* conv_w    = (const float*)d_in[14];
  const float* conv_b    = (const float*)d_in[15];
  const float* A         = (const float*)d_in[16];
  const float* Bm        = (const float*)d_in[17];
  const float* out_w     = (const float*)d_in[18];
  const float* out_b     = (const float*)d_in[19];
  const float* post_ln_w = (const float*)d_in[20];
  const float* post_ln_b = (const float*)d_in[21];
  const float* m1_w      = (const float*)d_in[22];
  const float* m1_b      = (const float*)d_in[23];
  const float* m2_w      = (const float*)d_in[24];
  const float* m2_b      = (const float*)d_in[25];
  const float* m3_w      = (const float*)d_in[26];
  const float* m3_b      = (const float*)d_in[27];
  float* outp = (float*)d_out;

  float* wsf = (float*)d_ws;
  size_t o = 0;
  auto F32 = [&](size_t n) { float* p = wsf + o; o += (n + 63) & ~(size_t)63; return p; };
  float* psum   = F32(1048576);
  float* psq    = F32(1048576);
  float* z2mx   = F32(1048576);
  float* z2mn   = F32(1048576);
  float* mom    = F32(65536);
  float* msd    = F32(65536);
  float* cc     = F32(512);
  float* s2t2   = F32(256);
  float* pstat  = F32(512);
  float* prs    = F32(8192);
  float* prq    = F32(8192);
  u16*   W2B    = (u16*)F32(8192);      // 16384 bf16
  float* fprojT = F32(32768);
  u16*   inwB   = (u16*)F32(524288);    // 1048576 bf16
  u16*   outwB  = (u16*)F32(262144);    // 524288 bf16
  u16*   albB   = (u16*)F32(32768);     // 65536 bf16
  u16*   BmT    = (u16*)F32(16384);     // 32768 bf16
  float* seqA   = F32(2097152);
  float* seqB   = F32(2097152);
  u16*   gateB  = (u16*)F32(2097152);   // 8192x512 bf16
  u16*   updB   = (u16*)F32(2097152);
  u16*   uB     = (u16*)F32(2097152);
  float* buv    = F32(131072);
  float* hstv   = F32(131072);
  float* pooled = F32(4096);
  float* e1     = F32(16384);
  float* e2     = F32(16384);
  float* e3     = F32(8192);
  if (ws_size < o * sizeof(float)) return;

  const float invM = 1.f / (float)(NFRM * NPT);

  k_prep<<<6720, 256, 0, stream>>>(conv2_w, fproj_w, in_w, out_w, A, Bm,
                                   W2B, fprojT, inwB, outwB, albB, BmT);
  k_mom<<<2048, 256, 0, stream>>>(x, mom, msd);
  k_stats1<<<64, 256, 0, stream>>>(mom, pstat);
  k_stats2<<<1, 256, 0, stream>>>(pstat, conv1_w, bn1_w, bn1_b, cc);
  k2_main<<<NFRM / 4, 256, 0, stream>>>(x, (const float4*)cc, (const float4*)msd, W2B,
                                        z2mx, z2mn, psum, psq);
  k_red1<<<64, 256, 0, stream>>>(psum, psq, prs, prq);
  k_red2<<<1, 256, 0, stream>>>(prs, prq, bn2_w, bn2_b, s2t2, invM, 1e-5f);
  k4_feat<<<NFRM / 8, 256, 0, stream>>>(z2mx, z2mn, s2t2, fprojT, fproj_b, pre_ln_w, pre_ln_b, seqA);

  for (int l = 0; l < NL; ++l) {
    const float* sin = (l & 1) ? seqB : seqA;
    float* sout      = (l & 1) ? seqA : seqB;
    k_in<<<NFRM / 32, 512, 0, stream>>>(sin, inwB + (size_t)l * 262144, in_b + l * 1024, gateB, updB);
    k_conv<<<NFRM * HH / 256, 256, 0, stream>>>(updB, conv_w + l * 2048, conv_b + l * 512, uB);
    k_bu<<<NFRM / 64, 256, 0, stream>>>(uB, BmT + (size_t)l * 8192, lengths, buv);
    k_scan<<<64, 256, 0, stream>>>(buv, hstv);
    k_out<<<NFRM / 32, 256, 0, stream>>>(hstv, gateB, albB + (size_t)l * 16384,
                                         outwB + (size_t)l * 131072, out_b + l * 256, lengths, sout);
  }
  k_postln<<<NFRM / 4, 256, 0, stream>>>(seqA, post_ln_w, post_ln_b, seqB);
  k_pool<<<16, 256, 0, stream>>>(seqB, lengths, pooled);
  k_mlp<<<256, 256, 0, stream>>>(pooled, m1_w, m1_b, e1, 256, 1024, 1);
  k_mlp<<<256, 256, 0, stream>>>(e1, m2_w, m2_b, e2, 1024, 1024, 1);
  k_mlp<<<128, 256, 0, stream>>>(e2, m3_w, m3_b, e3, 1024, 512, 0);
  k_norm<<<16, 256, 0, stream>>>(e3, outp);
}